// Round 18
// baseline (419.614 us; speedup 1.0000x reference)
//
#include <hip/hip_runtime.h>
#include <hip/hip_fp16.h>
#include <cstdint>
#include <cstddef>

// ---------------------------------------------------------------------------
// TopoGNN: 3x SAGEConv(mean) + BN + ReLU, softmax-attention pooling, 2 heads.
// N=100000 nodes, E=1600000 edges, B=64 segments, IN_CH=6, HID=64.
// R5 (754us) bucket-CSR. R7 (644us) bn_pool. R8 (593us) split matmul+BN-fly.
// R9 (529us) fp16 rows. R12 (474us) MFMA GEMM. R15 (409us) stats 64-slot.
// R17 (381us): group-per-node fp8 gather, no shfl. Top-5 is now the harness
//     workspace poison (268MB fills); all our kernels < 41us.
// R18: csr_sage1 = csr_local + layer-1 aggregation+matmul. The edge pass that
//     scatters eidx also gathers x[src] (edge-parallel, latency-hidden) into
//     a 6KB LDS tile (ds_add_f32); after the barrier each thread does the
//     6->64 matmul and writes hA. Kills sage1_fused's serial per-thread
//     gather (16 dependent L2 round-trips/node @ 1.5 blocks/CU).
// ---------------------------------------------------------------------------

#define EPB 8192   // edges per partition block (256 thr x 32)
#define NBIN 512   // padded bucket count (actual NB = ceil(N/256) <= 512)
#define EPS_BN 1e-5f

typedef _Float16 f16x8 __attribute__((ext_vector_type(8)));
typedef float    f32x4 __attribute__((ext_vector_type(4)));
typedef float    f32x2 __attribute__((ext_vector_type(2)));

// ---- phase A: per-block bucket histogram ---------------------------------
__global__ __launch_bounds__(256) void bucket_hist(const int* __restrict__ dst,
                                                   int* __restrict__ blockBin,
                                                   int* __restrict__ binTotal, int E)
{
    __shared__ int hist[NBIN];
    int t = threadIdx.x;
    for (int i = t; i < NBIN; i += 256) hist[i] = 0;
    __syncthreads();
    int e0 = blockIdx.x * EPB;
#pragma unroll
    for (int k = 0; k < 32; k++) {
        int e = e0 + (k << 8) + t;
        if (e < E) atomicAdd(&hist[dst[e] >> 8], 1);
    }
    __syncthreads();
    for (int i = t; i < NBIN; i += 256) {
        int c = hist[i];
        blockBin[blockIdx.x * NBIN + i] = c;
        if (c) atomicAdd(&binTotal[i], c);
    }
}

// ---- phase B1: single-block scan of the 512 bin totals --------------------
__global__ __launch_bounds__(512) void bin_scan_totals(const int* __restrict__ binTotal,
                                                       int* __restrict__ binBase,
                                                       int* __restrict__ rowptrN)
{
    __shared__ int s[NBIN];
    int t = threadIdx.x;
    int tot = binTotal[t];
    s[t] = tot;
    __syncthreads();
    for (int off = 1; off < NBIN; off <<= 1) {
        int v = (t >= off) ? s[t - off] : 0;
        __syncthreads();
        s[t] += v;
        __syncthreads();
    }
    binBase[t] = s[t] - tot;
    if (t == NBIN - 1) { binBase[NBIN] = s[t]; *rowptrN = s[t]; }
}

// ---- phase B2: per-bin exclusive scan over block counts (wave per bin) ----
__global__ __launch_bounds__(256) void blockbin_offs(int* __restrict__ blockBin,
                                                     const int* __restrict__ binBase,
                                                     int nBlk)
{
    int wv   = threadIdx.x >> 6;
    int lane = threadIdx.x & 63;
    int bin  = blockIdx.x * 4 + wv;
    int carry = binBase[bin];
    for (int c0 = 0; c0 < nBlk; c0 += 64) {
        int blk = c0 + lane;
        int cnt = (blk < nBlk) ? blockBin[blk * NBIN + bin] : 0;
        int v = cnt;
#pragma unroll
        for (int d = 1; d < 64; d <<= 1) {
            int u = __shfl_up(v, d, 64);
            if (lane >= d) v += u;
        }
        if (blk < nBlk) blockBin[blk * NBIN + bin] = carry + v - cnt;
        carry += __shfl(v, 63, 64);
    }
}

// ---- phase C: place packed (src | local_dst<<24); per-block LDS cursors ---
__global__ __launch_bounds__(256) void bucket_scatter(const int* __restrict__ src,
                                                      const int* __restrict__ dst,
                                                      const int* __restrict__ blockBin,
                                                      int* __restrict__ epck, int E)
{
    __shared__ int cur[NBIN];
    int t = threadIdx.x;
    for (int i = t; i < NBIN; i += 256) cur[i] = blockBin[blockIdx.x * NBIN + i];
    __syncthreads();
    int e0 = blockIdx.x * EPB;
#pragma unroll
    for (int k = 0; k < 32; k++) {
        int e = e0 + (k << 8) + t;
        if (e < E) {
            int d = dst[e];
            int pos = atomicAdd(&cur[d >> 8], 1);
            epck[pos] = src[e] | ((d & 255) << 24);   // src < 2^24
        }
    }
}

// ---- phase D + layer 1: per-bucket local CSR + fused 6ch agg + matmul -----
// Edge pass scatters eidx AND accumulates x[src] (6ch) into LDS per local
// dst (ds_add_f32, edge-parallel). Then each thread does the 6->64 matmul.
__global__ __launch_bounds__(256) void csr_sage1(
    const int* __restrict__ epck, const int* __restrict__ binBase,
    const float* __restrict__ x,
    const float* __restrict__ Wl, const float* __restrict__ bias,
    const float* __restrict__ Wr,
    int* __restrict__ rowptr, int* __restrict__ eidx,
    float* __restrict__ out, int N)
{
    __shared__ int    cnt[256], scn[256], cur[256];
    __shared__ float  a6[256 * 6];
    __shared__ float4 sWl[96], sWr[96];
    int t = threadIdx.x, bkt = blockIdx.x;
    int base = binBase[bkt], nE = binBase[bkt + 1] - base;
    cnt[t] = 0;
    if (t < 96) { sWl[t] = ((const float4*)Wl)[t]; sWr[t] = ((const float4*)Wr)[t]; }
    for (int i = t; i < 1536; i += 256) a6[i] = 0.f;
    __syncthreads();
    for (int j = t; j < nE; j += 256)
        atomicAdd(&cnt[(unsigned)epck[base + j] >> 24], 1);
    __syncthreads();
    scn[t] = cnt[t];
    __syncthreads();
    for (int off = 1; off < 256; off <<= 1) {
        int v = (t >= off) ? scn[t - off] : 0;
        __syncthreads();
        scn[t] += v;
        __syncthreads();
    }
    int excl = scn[t] - cnt[t];
    cur[t] = excl;
    int node = (bkt << 8) + t;
    if (node < N) rowptr[node] = base + excl;
    __syncthreads();
    for (int j = t; j < nE; j += 256) {
        int v  = epck[base + j];
        int dl = (unsigned)v >> 24;
        int s_ = v & 0xFFFFFF;
        int pos = atomicAdd(&cur[dl], 1);
        eidx[base + pos] = s_;                       // 16KB span: stays in L2
        const float2* r = (const float2*)(x + (size_t)s_ * 6);
        float2 r0 = r[0], r1 = r[1], r2 = r[2];
        atomicAdd(&a6[dl * 6 + 0], r0.x); atomicAdd(&a6[dl * 6 + 1], r0.y);
        atomicAdd(&a6[dl * 6 + 2], r1.x); atomicAdd(&a6[dl * 6 + 3], r1.y);
        atomicAdd(&a6[dl * 6 + 4], r2.x); atomicAdd(&a6[dl * 6 + 5], r2.y);
    }
    __syncthreads();
    if (node >= N) return;

    float invd = 1.0f / fmaxf((float)cnt[t], 1.0f);
    float a[6];
#pragma unroll
    for (int k = 0; k < 6; k++) a[k] = a6[t * 6 + k] * invd;

    const float2* xr2 = (const float2*)(x + (size_t)node * 6);
    float2 x0 = xr2[0], x1 = xr2[1], x2 = xr2[2];
    float hh[6] = {x0.x, x0.y, x1.x, x1.y, x2.x, x2.y};

    float4 acc[16];
#pragma unroll
    for (int cg = 0; cg < 16; cg++) acc[cg] = ((const float4*)bias)[cg];
#pragma unroll
    for (int k = 0; k < 6; k++) {
        float am = a[k];
        float hk = hh[k];
#pragma unroll
        for (int cg = 0; cg < 16; cg++) {
            float4 wl = sWl[k * 16 + cg];
            float4 wr = sWr[k * 16 + cg];
            acc[cg].x = fmaf(am, wl.x, fmaf(hk, wr.x, acc[cg].x));
            acc[cg].y = fmaf(am, wl.y, fmaf(hk, wr.y, acc[cg].y));
            acc[cg].z = fmaf(am, wl.z, fmaf(hk, wr.z, acc[cg].z));
            acc[cg].w = fmaf(am, wl.w, fmaf(hk, wr.w, acc[cg].w));
        }
    }
    float4* orow = (float4*)(out + (size_t)node * 64);
#pragma unroll
    for (int cg = 0; cg < 16; cg++) orow[cg] = acc[cg];
}

// ---- w_prep: pack [Wl;Wr] (fp32) into fragment-ordered fp16 ---------------
__global__ __launch_bounds__(256) void w_prep(const float* __restrict__ Wl,
                                              const float* __restrict__ Wr,
                                              __half* __restrict__ wf)
{
    int i = blockIdx.x * 256 + threadIdx.x;
    if (i >= 8192) return;
    int j    = i & 7;
    int m    = (i >> 3) & 15;
    int quad = (i >> 7) & 3;
    int tt   = (i >> 9) & 3;
    int q    = i >> 11;
    int k    = (q & 1) * 32 + quad * 8 + j;
    int col  = tt * 16 + m;
    const float* W = (q < 2) ? Wl : Wr;
    wf[i] = __float2half_rn(W[k * 64 + col]);
}

// ---- BN stats (separate pass — layer 1 only) ------------------------------
__global__ __launch_bounds__(256) void bn_stats(const float* __restrict__ h,
                                                float* __restrict__ stats, size_t total)
{
    __shared__ float ls[64], lss[64];
    if (threadIdx.x < 64) { ls[threadIdx.x] = 0.f; lss[threadIdx.x] = 0.f; }
    __syncthreads();
    float s = 0.f, ss = 0.f;
    size_t stride = (size_t)gridDim.x * 256;
    for (size_t i = (size_t)blockIdx.x * 256 + threadIdx.x; i < total; i += stride) {
        float v = h[i];
        s += v;
        ss = fmaf(v, v, ss);
    }
    int c = threadIdx.x & 63;
    atomicAdd(&ls[c], s);
    atomicAdd(&lss[c], ss);
    __syncthreads();
    if (threadIdx.x < 64) {
        unsafeAtomicAdd(&stats[threadIdx.x], ls[threadIdx.x]);
        unsafeAtomicAdd(&stats[64 + threadIdx.x], lss[threadIdx.x]);
    }
}

// ---- stats_reduce: fold 64 scratch slots into stats[128] ------------------
__global__ __launch_bounds__(128) void stats_reduce(const float* __restrict__ tmp,
                                                    float* __restrict__ stats)
{
    int t = threadIdx.x;       // 0..127
    float s = 0.f;
#pragma unroll 8
    for (int k = 0; k < 64; k++) s += tmp[k * 128 + t];
    stats[t] = s;
}

// ---- bn_dual: v = relu(bn(h)); h16 = fp16(v) (mm self-term), h8 = fp8(v)
//      (gather rows). 4 channels per thread.
__global__ __launch_bounds__(256) void bn_dual(const float* __restrict__ h,
                                               const float* __restrict__ stats,
                                               const float* __restrict__ g,
                                               const float* __restrict__ be,
                                               __half* __restrict__ h16,
                                               unsigned* __restrict__ h8,
                                               float invN, size_t total)
{
    size_t i4 = (size_t)blockIdx.x * 256 + threadIdx.x;
    if (i4 * 4 >= total) return;
    int c0 = (int)((i4 * 4) & 63);       // multiple of 4
    float v[4];
    float4 hv = ((const float4*)h)[i4];
    float hh[4] = {hv.x, hv.y, hv.z, hv.w};
#pragma unroll
    for (int j = 0; j < 4; j++) {
        int c = c0 + j;
        float mu  = stats[c] * invN;
        float var = stats[64 + c] * invN - mu * mu;
        float sc  = g[c] / sqrtf(var + EPS_BN);
        float sh  = fmaf(-mu, sc, be[c]);
        v[j] = fmaxf(fmaf(hh[j], sc, sh), 0.f);
    }
    float2 o16;
    ((__half2*)&o16)[0] = __floats2half2_rn(v[0], v[1]);
    ((__half2*)&o16)[1] = __floats2half2_rn(v[2], v[3]);
    ((float2*)h16)[i4] = o16;
    int p = __builtin_amdgcn_cvt_pk_fp8_f32(v[0], v[1], 0, false);
    p     = __builtin_amdgcn_cvt_pk_fp8_f32(v[2], v[3], p, true);
    h8[i4] = (unsigned)p;
}

// ---- pull aggregation, group-per-node: wave = 4 nodes x 16 lanes ----------
__global__ __launch_bounds__(256) void aggpull8(const int* __restrict__ rowptr,
                                                const int* __restrict__ eidx,
                                                const unsigned* __restrict__ h8,
                                                __half* __restrict__ agg16, int n)
{
    int wid  = (blockIdx.x * 256 + threadIdx.x) >> 6;
    int lane = threadIdx.x & 63;
    int grp  = lane >> 4;           // 0..3: node within wave
    int cq   = lane & 15;           // channel quad (4 ch per lane)
    int node = wid * 4 + grp;
    if (node >= n) return;
    int b = rowptr[node], e = rowptr[node + 1];

    float4 a0 = {0,0,0,0}, a1 = {0,0,0,0}, a2 = {0,0,0,0}, a3 = {0,0,0,0};

#define EDGE(S, ACC)                                                            \
    {                                                                           \
        unsigned r_ = h8[(size_t)(S) * 16 + cq];                                \
        f32x2 lo_ = __builtin_amdgcn_cvt_pk_f32_fp8(r_, false);                 \
        f32x2 hi_ = __builtin_amdgcn_cvt_pk_f32_fp8(r_, true);                  \
        ACC.x += lo_[0]; ACC.y += lo_[1]; ACC.z += hi_[0]; ACC.w += hi_[1];     \
    }

    int j = b;
    for (; j + 4 <= e; j += 4) {
        int s0 = eidx[j], s1 = eidx[j + 1], s2 = eidx[j + 2], s3 = eidx[j + 3];
        EDGE(s0, a0) EDGE(s1, a1) EDGE(s2, a2) EDGE(s3, a3)
    }
    for (; j < e; j++) {
        int s = eidx[j];
        EDGE(s, a0)
    }
#undef EDGE

    float ax = a0.x + a1.x + a2.x + a3.x;
    float ay = a0.y + a1.y + a2.y + a3.y;
    float az = a0.z + a1.z + a2.z + a3.z;
    float aw = a0.w + a1.w + a2.w + a3.w;
    float invd = 1.0f / fmaxf((float)(e - b), 1.0f);
    __half2 o01 = __floats2half2_rn(ax * invd, ay * invd);
    __half2 o23 = __floats2half2_rn(az * invd, aw * invd);
    float2 ov;
    ((__half2*)&ov)[0] = o01;
    ((__half2*)&ov)[1] = o23;
    ((float2*)(agg16 + (size_t)node * 64))[cq] = ov;
}

// ---- MFMA GEMM + fused BN stats (64-slot scratch, low contention) ---------
__global__ __launch_bounds__(256) void mm_mfma(
    const __half* __restrict__ agg16, const __half* __restrict__ h16,
    const __half* __restrict__ wfh, const float* __restrict__ bias,
    float* __restrict__ out, float* __restrict__ statsTmp, int n)
{
    __shared__ float ls[64], lss[64];
    int t = threadIdx.x;
    if (t < 64) { ls[t] = 0.f; lss[t] = 0.f; }
    __syncthreads();

    int wv = t >> 6, lane = t & 63;
    int m = lane & 15, quad = lane >> 4;
    int node0 = (blockIdx.x * 4 + wv) * 16;

    if (node0 < n) {
        const f16x8* wf = (const f16x8*)wfh;   // frag idx ((q*4+tt)*4+quad)*16+m

        int nodeA = node0 + m;
        if (nodeA >= n) nodeA = n - 1;         // tail-safe loads

        const _Float16* arow = (const _Float16*)(agg16 + (size_t)nodeA * 64);
        const _Float16* hrow = (const _Float16*)(h16   + (size_t)nodeA * 64);
        f16x8 af[4];
        af[0] = *(const f16x8*)(arow + quad * 8);
        af[1] = *(const f16x8*)(arow + 32 + quad * 8);
        af[2] = *(const f16x8*)(hrow + quad * 8);
        af[3] = *(const f16x8*)(hrow + 32 + quad * 8);

#pragma unroll
        for (int tt = 0; tt < 4; tt++) {
            float bv = bias[tt * 16 + m];
            f32x4 c = {bv, bv, bv, bv};
#pragma unroll
            for (int q = 0; q < 4; q++)
                c = __builtin_amdgcn_mfma_f32_16x16x32_f16(
                        af[q], wf[((q * 4 + tt) * 4 + quad) * 16 + m], c, 0, 0, 0);
            float s = 0.f, ss = 0.f;
#pragma unroll
            for (int r = 0; r < 4; r++) {
                int row = node0 + quad * 4 + r;
                float v = (row < n) ? c[r] : 0.f;
                if (row < n) out[(size_t)row * 64 + tt * 16 + m] = v;
                s += v;
                ss = fmaf(v, v, ss);
            }
            s  += __shfl_xor(s, 16, 64);  s  += __shfl_xor(s, 32, 64);
            ss += __shfl_xor(ss, 16, 64); ss += __shfl_xor(ss, 32, 64);
            if (quad == 0) {
                atomicAdd(&ls[tt * 16 + m], s);
                atomicAdd(&lss[tt * 16 + m], ss);
            }
        }
    }
    __syncthreads();
    if (t < 64) {
        float* slot = statsTmp + (size_t)(blockIdx.x & 63) * 128;
        unsafeAtomicAdd(&slot[t], ls[t]);
        unsafeAtomicAdd(&slot[64 + t], lss[t]);
    }
}

// ---- fused layer-3 BN+ReLU + attention-weighted segment pooling -----------
__global__ __launch_bounds__(256) void bn_pool(
    const float* __restrict__ h, const float* __restrict__ stats,
    const float* __restrict__ g, const float* __restrict__ be,
    const float* __restrict__ x, const int* __restrict__ batch,
    float* __restrict__ rawpool, float invN, int N, int chunk)
{
    int wid  = blockIdx.x * 4 + (threadIdx.x >> 6);
    int lane = threadIdx.x & 63;
    int i0 = wid * chunk;
    if (i0 >= N) return;
    int i1 = min(i0 + chunk, N);

    float mu  = stats[lane] * invN;
    float var = stats[64 + lane] * invN - mu * mu;
    float sc  = g[lane] / sqrtf(var + EPS_BN);
    float sh  = fmaf(-mu, sc, be[lane]);

    int   cur = batch[i0];
    float acc = 0.f;
    for (int i = i0; i < i1; i++) {
        int bi = batch[i];
        if (bi != cur) {
            unsafeAtomicAdd(&rawpool[cur * 64 + lane], acc);
            acc = 0.f;
            cur = bi;
        }
        float w = expf(x[(size_t)i * 6 + 4]);
        float v = fmaxf(fmaf(h[(size_t)i * 64 + lane], sc, sh), 0.f);
        acc = fmaf(v, w, acc);
    }
    unsafeAtomicAdd(&rawpool[cur * 64 + lane], acc);
}

// ---- softmax denominator (shift-invariant: min-sub + 1e-8 drop out) -------
__global__ __launch_bounds__(256) void softmax_sum(const float* __restrict__ x,
                                                   float* __restrict__ sumexp, int n)
{
    float s = 0.f;
    int stride = gridDim.x * 256;
    for (int i = blockIdx.x * 256 + threadIdx.x; i < n; i += stride)
        s += expf(x[(size_t)i * 6 + 4]);
#pragma unroll
    for (int o = 32; o > 0; o >>= 1) s += __shfl_down(s, o, 64);
    __shared__ float wsum[4];
    if ((threadIdx.x & 63) == 0) wsum[threadIdx.x >> 6] = s;
    __syncthreads();
    if (threadIdx.x == 0)
        unsafeAtomicAdd(sumexp, wsum[0] + wsum[1] + wsum[2] + wsum[3]);
}

__global__ void seg_bounds(const int* __restrict__ batch, int* __restrict__ lb, int n)
{
    int b = threadIdx.x;
    if (b > 64) return;
    int lo = 0, hi = n;
    while (lo < hi) {
        int mid = (lo + hi) >> 1;
        if (batch[mid] < b) lo = mid + 1; else hi = mid;
    }
    lb[b] = lo;
}

// ---- heads: normalize rawpool by 1/sumexp and counts, then 2 tiny MLPs ----
__global__ __launch_bounds__(64) void heads_kernel(
    const float* __restrict__ rawpool, const float* __restrict__ sumexp,
    const int* __restrict__ lb,
    const float* __restrict__ phW1, const float* __restrict__ phb1,
    const float* __restrict__ phW2, const float* __restrict__ phb2,
    const float* __restrict__ trW1, const float* __restrict__ trb1,
    const float* __restrict__ trW2, const float* __restrict__ trb2,
    float* __restrict__ out)
{
    int b = blockIdx.x, t = threadIdx.x;
    __shared__ float p[64], h1[32], h2[16];
    float cnt = (float)(lb[b + 1] - lb[b]);
    p[t] = rawpool[b * 64 + t] / (sumexp[0] * fmaxf(cnt, 1.0f));
    __syncthreads();
    if (t < 32) {
        float s = phb1[t];
        for (int k = 0; k < 64; k++) s = fmaf(p[k], phW1[k * 32 + t], s);
        h1[t] = fmaxf(s, 0.f);
    } else if (t < 48) {
        int tt = t - 32;
        float s = trb1[tt];
        for (int k = 0; k < 64; k++) s = fmaf(p[k], trW1[k * 16 + tt], s);
        h2[tt] = fmaxf(s, 0.f);
    }
    __syncthreads();
    if (t < 3) {
        float s = phb2[t];
        for (int k = 0; k < 32; k++) s = fmaf(h1[k], phW2[k * 3 + t], s);
        out[b * 3 + t] = s;
    } else if (t == 63) {
        float s = trb2[0];
        for (int k = 0; k < 16; k++) s = fmaf(h2[k], trW2[k], s);
        out[192 + b] = 1.0f / (1.0f + expf(-s));
    }
}

extern "C" void kernel_launch(void* const* d_in, const int* in_sizes, int n_in,
                              void* d_out, int out_size, void* d_ws, size_t ws_size,
                              hipStream_t stream)
{
    const float* x     = (const float*)d_in[0];
    const int*   ei    = (const int*)d_in[1];
    const int*   batch = (const int*)d_in[2];
    const float* W1l = (const float*)d_in[3];
    const float* b1  = (const float*)d_in[4];
    const float* W1r = (const float*)d_in[5];
    const float* W2l = (const float*)d_in[6];
    const float* b2  = (const float*)d_in[7];
    const float* W2r = (const float*)d_in[8];
    const float* W3l = (const float*)d_in[9];
    const float* b3  = (const float*)d_in[10];
    const float* W3r = (const float*)d_in[11];
    const float* g1  = (const float*)d_in[12];
    const float* be1 = (const float*)d_in[13];
    const float* g2  = (const float*)d_in[14];
    const float* be2 = (const float*)d_in[15];
    const float* g3  = (const float*)d_in[16];
    const float* be3 = (const float*)d_in[17];
    const float* phW1 = (const float*)d_in[18];
    const float* phb1 = (const float*)d_in[19];
    const float* phW2 = (const float*)d_in[20];
    const float* phb2 = (const float*)d_in[21];
    const float* trW1 = (const float*)d_in[22];
    const float* trb1 = (const float*)d_in[23];
    const float* trW2 = (const float*)d_in[24];
    const float* trb2 = (const float*)d_in[25];

    const int N = in_sizes[0] / 6;
    const int E = in_sizes[1] / 2;
    const int* src = ei;
    const int* dst = ei + E;

    const int NB    = (N + 255) >> 8;          // 391 buckets
    const int nBlkA = (E + EPB - 1) / EPB;     // 196 partition blocks

    float* ws = (float*)d_ws;
    const size_t N64 = (size_t)N * 64;
    float*  hA      = ws;                          // N*64 fp32 (h1 raw, then h3 raw)
    float*  hB      = ws + N64;                    // N*64 fp32 (h2 raw)
    __half* agg16   = (__half*)(ws + 2 * N64);     // N*64 fp16
    __half* h16     = (__half*)(ws + 2 * N64 + N64 / 2);  // N*64 fp16
    int*   epck     = (int*)(ws + 3 * N64);        // E packed src|dl<<24
    int*   eidx     = epck + E;                    // E (CSR by dst)
    int*   blockBin = eidx + E;                    // nBlkA * NBIN
    // --- contiguous zero region: binTotal + stats + statsTmp + rawpool + sumexp
    int*   binTotal = blockBin + (size_t)nBlkA * NBIN;   // NBIN
    float* stats    = (float*)(binTotal + NBIN);   // 3 * 128
    float* statsTmp = stats + 384;                 // 2 * 64 * 128
    float* rawpool  = statsTmp + 16384;            // 64*64
    float* sumexp   = rawpool + 4096;              // 1 (pad 4)
    // --- end zero region ---
    int*   binBase  = (int*)(sumexp + 4);          // NBIN + 1
    int*   rowptr   = binBase + NBIN + 1;          // N + 1
    int*   lb       = rowptr + N + 1;              // 65 (pad 72)
    __half* wfrag2  = (__half*)(lb + 72);          // 8192 fp16
    __half* wfrag3  = wfrag2 + 8192;               // 8192 fp16
    unsigned* h8    = (unsigned*)(wfrag3 + 8192);  // N*16 dwords (fp8 rows)
    float* out      = (float*)d_out;

    const int aggBlocks  = (N + 15) / 16;          // 6250: 16 nodes/block
    const int mfmaBlocks = (N + 63) / 64;          // 1563 (4 x 16-node tiles/block)
    const int cvt4Blocks = (int)((N64 / 4 + 255) / 256);
    const int PBLK = 1024;                         // bn_pool blocks (4 waves each)
    const int chunk = (N + PBLK * 4 - 1) / (PBLK * 4);
    const float invN = 1.0f / (float)N;

    // ---- zero accumulators; independent reductions + weight packing first
    size_t zbytes = (char*)(sumexp + 4) - (char*)binTotal;
    hipMemsetAsync(binTotal, 0, zbytes, stream);
    softmax_sum<<<256, 256, 0, stream>>>(x, sumexp, N);
    seg_bounds<<<1, 128, 0, stream>>>(batch, lb, N);
    w_prep<<<32, 256, 0, stream>>>(W2l, W2r, wfrag2);
    w_prep<<<32, 256, 0, stream>>>(W3l, W3r, wfrag3);

    // ---- CSR build via bucket partition; layer 1 fused into phase D ----
    bucket_hist<<<nBlkA, 256, 0, stream>>>(dst, blockBin, binTotal, E);
    bin_scan_totals<<<1, NBIN, 0, stream>>>(binTotal, binBase, rowptr + N);
    blockbin_offs<<<NBIN / 4, 256, 0, stream>>>(blockBin, binBase, nBlkA);
    bucket_scatter<<<nBlkA, 256, 0, stream>>>(src, dst, blockBin, epck, E);
    csr_sage1<<<NB, 256, 0, stream>>>(epck, binBase, x, W1l, b1, W1r,
                                      rowptr, eidx, hA, N);

    // ---- layer 1 epilogue: stats1; h16+h8 ----
    bn_stats<<<1024, 256, 0, stream>>>(hA, stats, N64);
    bn_dual<<<cvt4Blocks, 256, 0, stream>>>(hA, stats, g1, be1, h16, h8, invN, N64);

    // ---- layer 2 (fp8 gather; stats2 fused into mm_mfma -> 64-slot scratch)
    aggpull8<<<aggBlocks, 256, 0, stream>>>(rowptr, eidx, h8, agg16, N);
    mm_mfma<<<mfmaBlocks, 256, 0, stream>>>(agg16, h16, wfrag2, b2, hB,
                                            statsTmp, N);
    stats_reduce<<<1, 128, 0, stream>>>(statsTmp, stats + 128);
    bn_dual<<<cvt4Blocks, 256, 0, stream>>>(hB, stats + 128, g2, be2, h16, h8,
                                            invN, N64);

    // ---- layer 3 (fp8 gather; stats3 fused into mm_mfma -> 64-slot scratch)
    aggpull8<<<aggBlocks, 256, 0, stream>>>(rowptr, eidx, h8, agg16, N);
    mm_mfma<<<mfmaBlocks, 256, 0, stream>>>(agg16, h16, wfrag3, b3, hA,
                                            statsTmp + 8192, N);
    stats_reduce<<<1, 128, 0, stream>>>(statsTmp + 8192, stats + 256);

    // ---- fused BN3 + attention pooling + heads ----
    bn_pool<<<PBLK, 256, 0, stream>>>(hA, stats + 256, g3, be3, x, batch,
                                      rawpool, invN, N, chunk);
    heads_kernel<<<64, 64, 0, stream>>>(rawpool, sumexp, lb,
                                        phW1, phb1, phW2, phb2,
                                        trW1, trb1, trW2, trb2, out);
}

// Round 19
// 380.698 us; speedup vs baseline: 1.1022x; 1.1022x over previous
//
#include <hip/hip_runtime.h>
#include <hip/hip_fp16.h>
#include <cstdint>
#include <cstddef>

// ---------------------------------------------------------------------------
// TopoGNN: 3x SAGEConv(mean) + BN + ReLU, softmax-attention pooling, 2 heads.
// N=100000 nodes, E=1600000 edges, B=64 segments, IN_CH=6, HID=64.
// R5 (754us) bucket-CSR. R7 (644us) bn_pool. R8 (593us) split matmul+BN-fly.
// R9 (529us) fp16 rows. R12 (474us) MFMA GEMM. R15 (409us) stats 64-slot.
// R17 (381us): group-per-node fp8 gather, no shfl.
// R18 FAILED (420us): fusing layer-1 into csr_local pinned the grid to 391
//     blocks -> 13% occupancy, latency-bound (84us). Same lesson as R4:
//     don't fuse into grid-limited kernels.
// R19: strict revert to R17 (best known).
// ---------------------------------------------------------------------------

#define EPB 8192   // edges per partition block (256 thr x 32)
#define NBIN 512   // padded bucket count (actual NB = ceil(N/256) <= 512)
#define EPS_BN 1e-5f

typedef _Float16 f16x8 __attribute__((ext_vector_type(8)));
typedef float    f32x4 __attribute__((ext_vector_type(4)));
typedef float    f32x2 __attribute__((ext_vector_type(2)));

// ---- phase A: per-block bucket histogram ---------------------------------
__global__ __launch_bounds__(256) void bucket_hist(const int* __restrict__ dst,
                                                   int* __restrict__ blockBin,
                                                   int* __restrict__ binTotal, int E)
{
    __shared__ int hist[NBIN];
    int t = threadIdx.x;
    for (int i = t; i < NBIN; i += 256) hist[i] = 0;
    __syncthreads();
    int e0 = blockIdx.x * EPB;
#pragma unroll
    for (int k = 0; k < 32; k++) {
        int e = e0 + (k << 8) + t;
        if (e < E) atomicAdd(&hist[dst[e] >> 8], 1);
    }
    __syncthreads();
    for (int i = t; i < NBIN; i += 256) {
        int c = hist[i];
        blockBin[blockIdx.x * NBIN + i] = c;
        if (c) atomicAdd(&binTotal[i], c);
    }
}

// ---- phase B1: single-block scan of the 512 bin totals --------------------
__global__ __launch_bounds__(512) void bin_scan_totals(const int* __restrict__ binTotal,
                                                       int* __restrict__ binBase,
                                                       int* __restrict__ rowptrN)
{
    __shared__ int s[NBIN];
    int t = threadIdx.x;
    int tot = binTotal[t];
    s[t] = tot;
    __syncthreads();
    for (int off = 1; off < NBIN; off <<= 1) {
        int v = (t >= off) ? s[t - off] : 0;
        __syncthreads();
        s[t] += v;
        __syncthreads();
    }
    binBase[t] = s[t] - tot;
    if (t == NBIN - 1) { binBase[NBIN] = s[t]; *rowptrN = s[t]; }
}

// ---- phase B2: per-bin exclusive scan over block counts (wave per bin) ----
__global__ __launch_bounds__(256) void blockbin_offs(int* __restrict__ blockBin,
                                                     const int* __restrict__ binBase,
                                                     int nBlk)
{
    int wv   = threadIdx.x >> 6;
    int lane = threadIdx.x & 63;
    int bin  = blockIdx.x * 4 + wv;
    int carry = binBase[bin];
    for (int c0 = 0; c0 < nBlk; c0 += 64) {
        int blk = c0 + lane;
        int cnt = (blk < nBlk) ? blockBin[blk * NBIN + bin] : 0;
        int v = cnt;
#pragma unroll
        for (int d = 1; d < 64; d <<= 1) {
            int u = __shfl_up(v, d, 64);
            if (lane >= d) v += u;
        }
        if (blk < nBlk) blockBin[blk * NBIN + bin] = carry + v - cnt;
        carry += __shfl(v, 63, 64);
    }
}

// ---- phase C: place packed (src | local_dst<<24); per-block LDS cursors ---
__global__ __launch_bounds__(256) void bucket_scatter(const int* __restrict__ src,
                                                      const int* __restrict__ dst,
                                                      const int* __restrict__ blockBin,
                                                      int* __restrict__ epck, int E)
{
    __shared__ int cur[NBIN];
    int t = threadIdx.x;
    for (int i = t; i < NBIN; i += 256) cur[i] = blockBin[blockIdx.x * NBIN + i];
    __syncthreads();
    int e0 = blockIdx.x * EPB;
#pragma unroll
    for (int k = 0; k < 32; k++) {
        int e = e0 + (k << 8) + t;
        if (e < E) {
            int d = dst[e];
            int pos = atomicAdd(&cur[d >> 8], 1);
            epck[pos] = src[e] | ((d & 255) << 24);   // src < 2^24
        }
    }
}

// ---- phase D: per-bucket local CSR --------------------------------------
__global__ __launch_bounds__(256) void csr_local(const int* __restrict__ epck,
                                                 const int* __restrict__ binBase,
                                                 int* __restrict__ rowptr,
                                                 int* __restrict__ eidx, int N)
{
    __shared__ int cnt[256], s[256], cur[256];
    int t = threadIdx.x, bkt = blockIdx.x;
    int base = binBase[bkt], nE = binBase[bkt + 1] - base;
    cnt[t] = 0;
    __syncthreads();
    for (int j = t; j < nE; j += 256)
        atomicAdd(&cnt[(unsigned)epck[base + j] >> 24], 1);
    __syncthreads();
    s[t] = cnt[t];
    __syncthreads();
    for (int off = 1; off < 256; off <<= 1) {
        int v = (t >= off) ? s[t - off] : 0;
        __syncthreads();
        s[t] += v;
        __syncthreads();
    }
    int excl = s[t] - cnt[t];
    cur[t] = excl;
    int node = (bkt << 8) + t;
    if (node < N) rowptr[node] = base + excl;
    __syncthreads();
    for (int j = t; j < nE; j += 256) {
        int v = epck[base + j];
        int pos = atomicAdd(&cur[(unsigned)v >> 24], 1);
        eidx[base + pos] = v & 0xFFFFFF;     // contiguous 16KB span: stays in L2
    }
}

// ---- w_prep: pack [Wl;Wr] (fp32) into fragment-ordered fp16 ---------------
__global__ __launch_bounds__(256) void w_prep(const float* __restrict__ Wl,
                                              const float* __restrict__ Wr,
                                              __half* __restrict__ wf)
{
    int i = blockIdx.x * 256 + threadIdx.x;
    if (i >= 8192) return;
    int j    = i & 7;
    int m    = (i >> 3) & 15;
    int quad = (i >> 7) & 3;
    int tt   = (i >> 9) & 3;
    int q    = i >> 11;
    int k    = (q & 1) * 32 + quad * 8 + j;
    int col  = tt * 16 + m;
    const float* W = (q < 2) ? Wl : Wr;
    wf[i] = __float2half_rn(W[k * 64 + col]);
}

// ---- layer 1: fused pull-aggregation (6 ch) + matmul (thread-per-node) ----
__global__ __launch_bounds__(256) void sage1_fused(
    const int* __restrict__ rowptr, const int* __restrict__ eidx,
    const float* __restrict__ x,
    const float* __restrict__ Wl, const float* __restrict__ bias,
    const float* __restrict__ Wr, float* __restrict__ out, int n)
{
    __shared__ float4 sWl[6 * 16];
    __shared__ float4 sWr[6 * 16];
    for (int i = threadIdx.x; i < 6 * 16; i += 256) {
        sWl[i] = ((const float4*)Wl)[i];
        sWr[i] = ((const float4*)Wr)[i];
    }
    __syncthreads();

    int node = blockIdx.x * 256 + threadIdx.x;
    if (node >= n) return;

    int b = rowptr[node], e = rowptr[node + 1];
    float a[6] = {0.f, 0.f, 0.f, 0.f, 0.f, 0.f};
    for (int j = b; j < e; j++) {
        int s = eidx[j];
        const float2* r = (const float2*)(x + (size_t)s * 6);
        float2 r0 = r[0], r1 = r[1], r2 = r[2];
        a[0] += r0.x; a[1] += r0.y; a[2] += r1.x;
        a[3] += r1.y; a[4] += r2.x; a[5] += r2.y;
    }
    float invd = 1.0f / fmaxf((float)(e - b), 1.0f);

    const float2* xr2 = (const float2*)(x + (size_t)node * 6);
    float2 x0 = xr2[0], x1 = xr2[1], x2 = xr2[2];
    float hh[6] = {x0.x, x0.y, x1.x, x1.y, x2.x, x2.y};

    float4 acc[16];
#pragma unroll
    for (int cg = 0; cg < 16; cg++) acc[cg] = ((const float4*)bias)[cg];
#pragma unroll
    for (int k = 0; k < 6; k++) {
        float am = a[k] * invd;
        float hk = hh[k];
#pragma unroll
        for (int cg = 0; cg < 16; cg++) {
            float4 wl = sWl[k * 16 + cg];
            float4 wr = sWr[k * 16 + cg];
            acc[cg].x = fmaf(am, wl.x, fmaf(hk, wr.x, acc[cg].x));
            acc[cg].y = fmaf(am, wl.y, fmaf(hk, wr.y, acc[cg].y));
            acc[cg].z = fmaf(am, wl.z, fmaf(hk, wr.z, acc[cg].z));
            acc[cg].w = fmaf(am, wl.w, fmaf(hk, wr.w, acc[cg].w));
        }
    }
    float4* orow = (float4*)(out + (size_t)node * 64);
#pragma unroll
    for (int cg = 0; cg < 16; cg++) orow[cg] = acc[cg];
}

// ---- BN stats (separate pass — layer 1 only) ------------------------------
__global__ __launch_bounds__(256) void bn_stats(const float* __restrict__ h,
                                                float* __restrict__ stats, size_t total)
{
    __shared__ float ls[64], lss[64];
    if (threadIdx.x < 64) { ls[threadIdx.x] = 0.f; lss[threadIdx.x] = 0.f; }
    __syncthreads();
    float s = 0.f, ss = 0.f;
    size_t stride = (size_t)gridDim.x * 256;
    for (size_t i = (size_t)blockIdx.x * 256 + threadIdx.x; i < total; i += stride) {
        float v = h[i];
        s += v;
        ss = fmaf(v, v, ss);
    }
    int c = threadIdx.x & 63;
    atomicAdd(&ls[c], s);
    atomicAdd(&lss[c], ss);
    __syncthreads();
    if (threadIdx.x < 64) {
        unsafeAtomicAdd(&stats[threadIdx.x], ls[threadIdx.x]);
        unsafeAtomicAdd(&stats[64 + threadIdx.x], lss[threadIdx.x]);
    }
}

// ---- stats_reduce: fold 64 scratch slots into stats[128] ------------------
__global__ __launch_bounds__(128) void stats_reduce(const float* __restrict__ tmp,
                                                    float* __restrict__ stats)
{
    int t = threadIdx.x;       // 0..127
    float s = 0.f;
#pragma unroll 8
    for (int k = 0; k < 64; k++) s += tmp[k * 128 + t];
    stats[t] = s;
}

// ---- bn_dual: v = relu(bn(h)); h16 = fp16(v) (mm self-term), h8 = fp8(v)
//      (gather rows). 4 channels per thread.
__global__ __launch_bounds__(256) void bn_dual(const float* __restrict__ h,
                                               const float* __restrict__ stats,
                                               const float* __restrict__ g,
                                               const float* __restrict__ be,
                                               __half* __restrict__ h16,
                                               unsigned* __restrict__ h8,
                                               float invN, size_t total)
{
    size_t i4 = (size_t)blockIdx.x * 256 + threadIdx.x;
    if (i4 * 4 >= total) return;
    int c0 = (int)((i4 * 4) & 63);       // multiple of 4
    float v[4];
    float4 hv = ((const float4*)h)[i4];
    float hh[4] = {hv.x, hv.y, hv.z, hv.w};
#pragma unroll
    for (int j = 0; j < 4; j++) {
        int c = c0 + j;
        float mu  = stats[c] * invN;
        float var = stats[64 + c] * invN - mu * mu;
        float sc  = g[c] / sqrtf(var + EPS_BN);
        float sh  = fmaf(-mu, sc, be[c]);
        v[j] = fmaxf(fmaf(hh[j], sc, sh), 0.f);
    }
    float2 o16;
    ((__half2*)&o16)[0] = __floats2half2_rn(v[0], v[1]);
    ((__half2*)&o16)[1] = __floats2half2_rn(v[2], v[3]);
    ((float2*)h16)[i4] = o16;
    int p = __builtin_amdgcn_cvt_pk_fp8_f32(v[0], v[1], 0, false);
    p     = __builtin_amdgcn_cvt_pk_fp8_f32(v[2], v[3], p, true);
    h8[i4] = (unsigned)p;
}

// ---- pull aggregation, group-per-node: wave = 4 nodes x 16 lanes ----------
// Each 16-lane group walks its own node's edges; eidx read group-uniform
// (HW broadcast); one dword = 4 fp8 channels; NO shfl, NO cross-lane reduce.
__global__ __launch_bounds__(256) void aggpull8(const int* __restrict__ rowptr,
                                                const int* __restrict__ eidx,
                                                const unsigned* __restrict__ h8,
                                                __half* __restrict__ agg16, int n)
{
    int wid  = (blockIdx.x * 256 + threadIdx.x) >> 6;
    int lane = threadIdx.x & 63;
    int grp  = lane >> 4;           // 0..3: node within wave
    int cq   = lane & 15;           // channel quad (4 ch per lane)
    int node = wid * 4 + grp;
    if (node >= n) return;
    int b = rowptr[node], e = rowptr[node + 1];

    float4 a0 = {0,0,0,0}, a1 = {0,0,0,0}, a2 = {0,0,0,0}, a3 = {0,0,0,0};

#define EDGE(S, ACC)                                                            \
    {                                                                           \
        unsigned r_ = h8[(size_t)(S) * 16 + cq];                                \
        f32x2 lo_ = __builtin_amdgcn_cvt_pk_f32_fp8(r_, false);                 \
        f32x2 hi_ = __builtin_amdgcn_cvt_pk_f32_fp8(r_, true);                  \
        ACC.x += lo_[0]; ACC.y += lo_[1]; ACC.z += hi_[0]; ACC.w += hi_[1];     \
    }

    int j = b;
    for (; j + 4 <= e; j += 4) {
        int s0 = eidx[j], s1 = eidx[j + 1], s2 = eidx[j + 2], s3 = eidx[j + 3];
        EDGE(s0, a0) EDGE(s1, a1) EDGE(s2, a2) EDGE(s3, a3)
    }
    for (; j < e; j++) {
        int s = eidx[j];
        EDGE(s, a0)
    }
#undef EDGE

    float ax = a0.x + a1.x + a2.x + a3.x;
    float ay = a0.y + a1.y + a2.y + a3.y;
    float az = a0.z + a1.z + a2.z + a3.z;
    float aw = a0.w + a1.w + a2.w + a3.w;
    float invd = 1.0f / fmaxf((float)(e - b), 1.0f);
    __half2 o01 = __floats2half2_rn(ax * invd, ay * invd);
    __half2 o23 = __floats2half2_rn(az * invd, aw * invd);
    float2 ov;
    ((__half2*)&ov)[0] = o01;
    ((__half2*)&ov)[1] = o23;
    ((float2*)(agg16 + (size_t)node * 64))[cq] = ov;
}

// ---- MFMA GEMM + fused BN stats (64-slot scratch, low contention) ---------
__global__ __launch_bounds__(256) void mm_mfma(
    const __half* __restrict__ agg16, const __half* __restrict__ h16,
    const __half* __restrict__ wfh, const float* __restrict__ bias,
    float* __restrict__ out, float* __restrict__ statsTmp, int n)
{
    __shared__ float ls[64], lss[64];
    int t = threadIdx.x;
    if (t < 64) { ls[t] = 0.f; lss[t] = 0.f; }
    __syncthreads();

    int wv = t >> 6, lane = t & 63;
    int m = lane & 15, quad = lane >> 4;
    int node0 = (blockIdx.x * 4 + wv) * 16;

    if (node0 < n) {
        const f16x8* wf = (const f16x8*)wfh;   // frag idx ((q*4+tt)*4+quad)*16+m

        int nodeA = node0 + m;
        if (nodeA >= n) nodeA = n - 1;         // tail-safe loads

        const _Float16* arow = (const _Float16*)(agg16 + (size_t)nodeA * 64);
        const _Float16* hrow = (const _Float16*)(h16   + (size_t)nodeA * 64);
        f16x8 af[4];
        af[0] = *(const f16x8*)(arow + quad * 8);
        af[1] = *(const f16x8*)(arow + 32 + quad * 8);
        af[2] = *(const f16x8*)(hrow + quad * 8);
        af[3] = *(const f16x8*)(hrow + 32 + quad * 8);

#pragma unroll
        for (int tt = 0; tt < 4; tt++) {
            float bv = bias[tt * 16 + m];
            f32x4 c = {bv, bv, bv, bv};
#pragma unroll
            for (int q = 0; q < 4; q++)
                c = __builtin_amdgcn_mfma_f32_16x16x32_f16(
                        af[q], wf[((q * 4 + tt) * 4 + quad) * 16 + m], c, 0, 0, 0);
            float s = 0.f, ss = 0.f;
#pragma unroll
            for (int r = 0; r < 4; r++) {
                int row = node0 + quad * 4 + r;
                float v = (row < n) ? c[r] : 0.f;
                if (row < n) out[(size_t)row * 64 + tt * 16 + m] = v;
                s += v;
                ss = fmaf(v, v, ss);
            }
            s  += __shfl_xor(s, 16, 64);  s  += __shfl_xor(s, 32, 64);
            ss += __shfl_xor(ss, 16, 64); ss += __shfl_xor(ss, 32, 64);
            if (quad == 0) {
                atomicAdd(&ls[tt * 16 + m], s);
                atomicAdd(&lss[tt * 16 + m], ss);
            }
        }
    }
    __syncthreads();
    if (t < 64) {
        float* slot = statsTmp + (size_t)(blockIdx.x & 63) * 128;
        unsafeAtomicAdd(&slot[t], ls[t]);
        unsafeAtomicAdd(&slot[64 + t], lss[t]);
    }
}

// ---- fused layer-3 BN+ReLU + attention-weighted segment pooling -----------
__global__ __launch_bounds__(256) void bn_pool(
    const float* __restrict__ h, const float* __restrict__ stats,
    const float* __restrict__ g, const float* __restrict__ be,
    const float* __restrict__ x, const int* __restrict__ batch,
    float* __restrict__ rawpool, float invN, int N, int chunk)
{
    int wid  = blockIdx.x * 4 + (threadIdx.x >> 6);
    int lane = threadIdx.x & 63;
    int i0 = wid * chunk;
    if (i0 >= N) return;
    int i1 = min(i0 + chunk, N);

    float mu  = stats[lane] * invN;
    float var = stats[64 + lane] * invN - mu * mu;
    float sc  = g[lane] / sqrtf(var + EPS_BN);
    float sh  = fmaf(-mu, sc, be[lane]);

    int   cur = batch[i0];
    float acc = 0.f;
    for (int i = i0; i < i1; i++) {
        int bi = batch[i];
        if (bi != cur) {
            unsafeAtomicAdd(&rawpool[cur * 64 + lane], acc);
            acc = 0.f;
            cur = bi;
        }
        float w = expf(x[(size_t)i * 6 + 4]);
        float v = fmaxf(fmaf(h[(size_t)i * 64 + lane], sc, sh), 0.f);
        acc = fmaf(v, w, acc);
    }
    unsafeAtomicAdd(&rawpool[cur * 64 + lane], acc);
}

// ---- softmax denominator (shift-invariant: min-sub + 1e-8 drop out) -------
__global__ __launch_bounds__(256) void softmax_sum(const float* __restrict__ x,
                                                   float* __restrict__ sumexp, int n)
{
    float s = 0.f;
    int stride = gridDim.x * 256;
    for (int i = blockIdx.x * 256 + threadIdx.x; i < n; i += stride)
        s += expf(x[(size_t)i * 6 + 4]);
#pragma unroll
    for (int o = 32; o > 0; o >>= 1) s += __shfl_down(s, o, 64);
    __shared__ float wsum[4];
    if ((threadIdx.x & 63) == 0) wsum[threadIdx.x >> 6] = s;
    __syncthreads();
    if (threadIdx.x == 0)
        unsafeAtomicAdd(sumexp, wsum[0] + wsum[1] + wsum[2] + wsum[3]);
}

__global__ void seg_bounds(const int* __restrict__ batch, int* __restrict__ lb, int n)
{
    int b = threadIdx.x;
    if (b > 64) return;
    int lo = 0, hi = n;
    while (lo < hi) {
        int mid = (lo + hi) >> 1;
        if (batch[mid] < b) lo = mid + 1; else hi = mid;
    }
    lb[b] = lo;
}

// ---- heads: normalize rawpool by 1/sumexp and counts, then 2 tiny MLPs ----
__global__ __launch_bounds__(64) void heads_kernel(
    const float* __restrict__ rawpool, const float* __restrict__ sumexp,
    const int* __restrict__ lb,
    const float* __restrict__ phW1, const float* __restrict__ phb1,
    const float* __restrict__ phW2, const float* __restrict__ phb2,
    const float* __restrict__ trW1, const float* __restrict__ trb1,
    const float* __restrict__ trW2, const float* __restrict__ trb2,
    float* __restrict__ out)
{
    int b = blockIdx.x, t = threadIdx.x;
    __shared__ float p[64], h1[32], h2[16];
    float cnt = (float)(lb[b + 1] - lb[b]);
    p[t] = rawpool[b * 64 + t] / (sumexp[0] * fmaxf(cnt, 1.0f));
    __syncthreads();
    if (t < 32) {
        float s = phb1[t];
        for (int k = 0; k < 64; k++) s = fmaf(p[k], phW1[k * 32 + t], s);
        h1[t] = fmaxf(s, 0.f);
    } else if (t < 48) {
        int tt = t - 32;
        float s = trb1[tt];
        for (int k = 0; k < 64; k++) s = fmaf(p[k], trW1[k * 16 + tt], s);
        h2[tt] = fmaxf(s, 0.f);
    }
    __syncthreads();
    if (t < 3) {
        float s = phb2[t];
        for (int k = 0; k < 32; k++) s = fmaf(h1[k], phW2[k * 3 + t], s);
        out[b * 3 + t] = s;
    } else if (t == 63) {
        float s = trb2[0];
        for (int k = 0; k < 16; k++) s = fmaf(h2[k], trW2[k], s);
        out[192 + b] = 1.0f / (1.0f + expf(-s));
    }
}

extern "C" void kernel_launch(void* const* d_in, const int* in_sizes, int n_in,
                              void* d_out, int out_size, void* d_ws, size_t ws_size,
                              hipStream_t stream)
{
    const float* x     = (const float*)d_in[0];
    const int*   ei    = (const int*)d_in[1];
    const int*   batch = (const int*)d_in[2];
    const float* W1l = (const float*)d_in[3];
    const float* b1  = (const float*)d_in[4];
    const float* W1r = (const float*)d_in[5];
    const float* W2l = (const float*)d_in[6];
    const float* b2  = (const float*)d_in[7];
    const float* W2r = (const float*)d_in[8];
    const float* W3l = (const float*)d_in[9];
    const float* b3  = (const float*)d_in[10];
    const float* W3r = (const float*)d_in[11];
    const float* g1  = (const float*)d_in[12];
    const float* be1 = (const float*)d_in[13];
    const float* g2  = (const float*)d_in[14];
    const float* be2 = (const float*)d_in[15];
    const float* g3  = (const float*)d_in[16];
    const float* be3 = (const float*)d_in[17];
    const float* phW1 = (const float*)d_in[18];
    const float* phb1 = (const float*)d_in[19];
    const float* phW2 = (const float*)d_in[20];
    const float* phb2 = (const float*)d_in[21];
    const float* trW1 = (const float*)d_in[22];
    const float* trb1 = (const float*)d_in[23];
    const float* trW2 = (const float*)d_in[24];
    const float* trb2 = (const float*)d_in[25];

    const int N = in_sizes[0] / 6;
    const int E = in_sizes[1] / 2;
    const int* src = ei;
    const int* dst = ei + E;

    const int NB    = (N + 255) >> 8;          // 391 buckets
    const int nBlkA = (E + EPB - 1) / EPB;     // 196 partition blocks

    float* ws = (float*)d_ws;
    const size_t N64 = (size_t)N * 64;
    float*  hA      = ws;                          // N*64 fp32 (h1 raw, then h3 raw)
    float*  hB      = ws + N64;                    // N*64 fp32 (h2 raw)
    __half* agg16   = (__half*)(ws + 2 * N64);     // N*64 fp16
    __half* h16     = (__half*)(ws + 2 * N64 + N64 / 2);  // N*64 fp16
    int*   epck     = (int*)(ws + 3 * N64);        // E packed src|dl<<24
    int*   eidx     = epck + E;                    // E (CSR by dst)
    int*   blockBin = eidx + E;                    // nBlkA * NBIN
    // --- contiguous zero region: binTotal + stats + statsTmp + rawpool + sumexp
    int*   binTotal = blockBin + (size_t)nBlkA * NBIN;   // NBIN
    float* stats    = (float*)(binTotal + NBIN);   // 3 * 128
    float* statsTmp = stats + 384;                 // 2 * 64 * 128
    float* rawpool  = statsTmp + 16384;            // 64*64
    float* sumexp   = rawpool + 4096;              // 1 (pad 4)
    // --- end zero region ---
    int*   binBase  = (int*)(sumexp + 4);          // NBIN + 1
    int*   rowptr   = binBase + NBIN + 1;          // N + 1
    int*   lb       = rowptr + N + 1;              // 65 (pad 72)
    __half* wfrag2  = (__half*)(lb + 72);          // 8192 fp16
    __half* wfrag3  = wfrag2 + 8192;               // 8192 fp16
    unsigned* h8    = (unsigned*)(wfrag3 + 8192);  // N*16 dwords (fp8 rows)
    float* out      = (float*)d_out;

    const int nodeBlocks = (N + 255) / 256;
    const int aggBlocks  = (N + 15) / 16;          // 6250: 16 nodes/block
    const int mfmaBlocks = (N + 63) / 64;          // 1563 (4 x 16-node tiles/block)
    const int cvt4Blocks = (int)((N64 / 4 + 255) / 256);
    const int PBLK = 1024;                         // bn_pool blocks (4 waves each)
    const int chunk = (N + PBLK * 4 - 1) / (PBLK * 4);
    const float invN = 1.0f / (float)N;

    // ---- zero accumulators; independent reductions + weight packing first
    size_t zbytes = (char*)(sumexp + 4) - (char*)binTotal;
    hipMemsetAsync(binTotal, 0, zbytes, stream);
    softmax_sum<<<256, 256, 0, stream>>>(x, sumexp, N);
    seg_bounds<<<1, 128, 0, stream>>>(batch, lb, N);
    w_prep<<<32, 256, 0, stream>>>(W2l, W2r, wfrag2);
    w_prep<<<32, 256, 0, stream>>>(W3l, W3r, wfrag3);

    // ---- CSR build via bucket partition ----
    bucket_hist<<<nBlkA, 256, 0, stream>>>(dst, blockBin, binTotal, E);
    bin_scan_totals<<<1, NBIN, 0, stream>>>(binTotal, binBase, rowptr + N);
    blockbin_offs<<<NBIN / 4, 256, 0, stream>>>(blockBin, binBase, nBlkA);
    bucket_scatter<<<nBlkA, 256, 0, stream>>>(src, dst, blockBin, epck, E);
    csr_local<<<NB, 256, 0, stream>>>(epck, binBase, rowptr, eidx, N);

    // ---- layer 1: agg6 + matmul -> hA raw; stats1; h16+h8 ----
    sage1_fused<<<nodeBlocks, 256, 0, stream>>>(rowptr, eidx, x, W1l, b1, W1r, hA, N);
    bn_stats<<<1024, 256, 0, stream>>>(hA, stats, N64);
    bn_dual<<<cvt4Blocks, 256, 0, stream>>>(hA, stats, g1, be1, h16, h8, invN, N64);

    // ---- layer 2 (fp8 gather; stats2 fused into mm_mfma -> 64-slot scratch)
    aggpull8<<<aggBlocks, 256, 0, stream>>>(rowptr, eidx, h8, agg16, N);
    mm_mfma<<<mfmaBlocks, 256, 0, stream>>>(agg16, h16, wfrag2, b2, hB,
                                            statsTmp, N);
    stats_reduce<<<1, 128, 0, stream>>>(statsTmp, stats + 128);
    bn_dual<<<cvt4Blocks, 256, 0, stream>>>(hB, stats + 128, g2, be2, h16, h8,
                                            invN, N64);

    // ---- layer 3 (fp8 gather; stats3 fused into mm_mfma -> 64-slot scratch)
    aggpull8<<<aggBlocks, 256, 0, stream>>>(rowptr, eidx, h8, agg16, N);
    mm_mfma<<<mfmaBlocks, 256, 0, stream>>>(agg16, h16, wfrag3, b3, hA,
                                            statsTmp + 8192, N);
    stats_reduce<<<1, 128, 0, stream>>>(statsTmp + 8192, stats + 256);

    // ---- fused BN3 + attention pooling + heads ----
    bn_pool<<<PBLK, 256, 0, stream>>>(hA, stats + 256, g3, be3, x, batch,
                                      rawpool, invN, N, chunk);
    heads_kernel<<<64, 64, 0, stream>>>(rawpool, sumexp, lb,
                                        phW1, phb1, phW2, phb2,
                                        trW1, trb1, trW2, trb2, out);
}

// Round 20
// 372.782 us; speedup vs baseline: 1.1256x; 1.0212x over previous
//
#include <hip/hip_runtime.h>
#include <hip/hip_fp16.h>
#include <cstdint>
#include <cstddef>

// ---------------------------------------------------------------------------
// TopoGNN: 3x SAGEConv(mean) + BN + ReLU, softmax-attention pooling, 2 heads.
// N=100000 nodes, E=1600000 edges, B=64 segments, IN_CH=6, HID=64.
// R5 (754us) bucket-CSR. R7 (644us) bn_pool. R8 (593us) split matmul+BN-fly.
// R9 (529us) fp16 rows. R12 (474us) MFMA GEMM. R15 (409us) stats 64-slot.
// R17/R19 (381us): group-per-node fp8 gather, no shfl. R18 FAILED (fusing
//     into 391-block csr_local: grid-limited latency).
// R20: agg_mm_mfma -- fuse aggregation into the MFMA GEMM via a per-wave
//     LDS tile (16 nodes x 64ch fp16, stride 72 halves for aligned b128
//     fragment reads). Kills the 25.6MB agg16 round-trip + 2 launches.
//     Unlike R18: 1563 blocks x 4 waves = 6.3K waves (~24/CU) keeps the
//     gather latency-hidden.
// ---------------------------------------------------------------------------

#define EPB 8192   // edges per partition block (256 thr x 32)
#define NBIN 512   // padded bucket count (actual NB = ceil(N/256) <= 512)
#define EPS_BN 1e-5f

typedef _Float16 f16x8 __attribute__((ext_vector_type(8)));
typedef float    f32x4 __attribute__((ext_vector_type(4)));
typedef float    f32x2 __attribute__((ext_vector_type(2)));

// ---- phase A: per-block bucket histogram ---------------------------------
__global__ __launch_bounds__(256) void bucket_hist(const int* __restrict__ dst,
                                                   int* __restrict__ blockBin,
                                                   int* __restrict__ binTotal, int E)
{
    __shared__ int hist[NBIN];
    int t = threadIdx.x;
    for (int i = t; i < NBIN; i += 256) hist[i] = 0;
    __syncthreads();
    int e0 = blockIdx.x * EPB;
#pragma unroll
    for (int k = 0; k < 32; k++) {
        int e = e0 + (k << 8) + t;
        if (e < E) atomicAdd(&hist[dst[e] >> 8], 1);
    }
    __syncthreads();
    for (int i = t; i < NBIN; i += 256) {
        int c = hist[i];
        blockBin[blockIdx.x * NBIN + i] = c;
        if (c) atomicAdd(&binTotal[i], c);
    }
}

// ---- phase B1: single-block scan of the 512 bin totals --------------------
__global__ __launch_bounds__(512) void bin_scan_totals(const int* __restrict__ binTotal,
                                                       int* __restrict__ binBase,
                                                       int* __restrict__ rowptrN)
{
    __shared__ int s[NBIN];
    int t = threadIdx.x;
    int tot = binTotal[t];
    s[t] = tot;
    __syncthreads();
    for (int off = 1; off < NBIN; off <<= 1) {
        int v = (t >= off) ? s[t - off] : 0;
        __syncthreads();
        s[t] += v;
        __syncthreads();
    }
    binBase[t] = s[t] - tot;
    if (t == NBIN - 1) { binBase[NBIN] = s[t]; *rowptrN = s[t]; }
}

// ---- phase B2: per-bin exclusive scan over block counts (wave per bin) ----
__global__ __launch_bounds__(256) void blockbin_offs(int* __restrict__ blockBin,
                                                     const int* __restrict__ binBase,
                                                     int nBlk)
{
    int wv   = threadIdx.x >> 6;
    int lane = threadIdx.x & 63;
    int bin  = blockIdx.x * 4 + wv;
    int carry = binBase[bin];
    for (int c0 = 0; c0 < nBlk; c0 += 64) {
        int blk = c0 + lane;
        int cnt = (blk < nBlk) ? blockBin[blk * NBIN + bin] : 0;
        int v = cnt;
#pragma unroll
        for (int d = 1; d < 64; d <<= 1) {
            int u = __shfl_up(v, d, 64);
            if (lane >= d) v += u;
        }
        if (blk < nBlk) blockBin[blk * NBIN + bin] = carry + v - cnt;
        carry += __shfl(v, 63, 64);
    }
}

// ---- phase C: place packed (src | local_dst<<24); per-block LDS cursors ---
__global__ __launch_bounds__(256) void bucket_scatter(const int* __restrict__ src,
                                                      const int* __restrict__ dst,
                                                      const int* __restrict__ blockBin,
                                                      int* __restrict__ epck, int E)
{
    __shared__ int cur[NBIN];
    int t = threadIdx.x;
    for (int i = t; i < NBIN; i += 256) cur[i] = blockBin[blockIdx.x * NBIN + i];
    __syncthreads();
    int e0 = blockIdx.x * EPB;
#pragma unroll
    for (int k = 0; k < 32; k++) {
        int e = e0 + (k << 8) + t;
        if (e < E) {
            int d = dst[e];
            int pos = atomicAdd(&cur[d >> 8], 1);
            epck[pos] = src[e] | ((d & 255) << 24);   // src < 2^24
        }
    }
}

// ---- phase D: per-bucket local CSR --------------------------------------
__global__ __launch_bounds__(256) void csr_local(const int* __restrict__ epck,
                                                 const int* __restrict__ binBase,
                                                 int* __restrict__ rowptr,
                                                 int* __restrict__ eidx, int N)
{
    __shared__ int cnt[256], s[256], cur[256];
    int t = threadIdx.x, bkt = blockIdx.x;
    int base = binBase[bkt], nE = binBase[bkt + 1] - base;
    cnt[t] = 0;
    __syncthreads();
    for (int j = t; j < nE; j += 256)
        atomicAdd(&cnt[(unsigned)epck[base + j] >> 24], 1);
    __syncthreads();
    s[t] = cnt[t];
    __syncthreads();
    for (int off = 1; off < 256; off <<= 1) {
        int v = (t >= off) ? s[t - off] : 0;
        __syncthreads();
        s[t] += v;
        __syncthreads();
    }
    int excl = s[t] - cnt[t];
    cur[t] = excl;
    int node = (bkt << 8) + t;
    if (node < N) rowptr[node] = base + excl;
    __syncthreads();
    for (int j = t; j < nE; j += 256) {
        int v = epck[base + j];
        int pos = atomicAdd(&cur[(unsigned)v >> 24], 1);
        eidx[base + pos] = v & 0xFFFFFF;     // contiguous 16KB span: stays in L2
    }
}

// ---- w_prep: pack [Wl;Wr] (fp32) into fragment-ordered fp16 ---------------
__global__ __launch_bounds__(256) void w_prep(const float* __restrict__ Wl,
                                              const float* __restrict__ Wr,
                                              __half* __restrict__ wf)
{
    int i = blockIdx.x * 256 + threadIdx.x;
    if (i >= 8192) return;
    int j    = i & 7;
    int m    = (i >> 3) & 15;
    int quad = (i >> 7) & 3;
    int tt   = (i >> 9) & 3;
    int q    = i >> 11;
    int k    = (q & 1) * 32 + quad * 8 + j;
    int col  = tt * 16 + m;
    const float* W = (q < 2) ? Wl : Wr;
    wf[i] = __float2half_rn(W[k * 64 + col]);
}

// ---- layer 1: fused pull-aggregation (6 ch) + matmul (thread-per-node) ----
__global__ __launch_bounds__(256) void sage1_fused(
    const int* __restrict__ rowptr, const int* __restrict__ eidx,
    const float* __restrict__ x,
    const float* __restrict__ Wl, const float* __restrict__ bias,
    const float* __restrict__ Wr, float* __restrict__ out, int n)
{
    __shared__ float4 sWl[6 * 16];
    __shared__ float4 sWr[6 * 16];
    for (int i = threadIdx.x; i < 6 * 16; i += 256) {
        sWl[i] = ((const float4*)Wl)[i];
        sWr[i] = ((const float4*)Wr)[i];
    }
    __syncthreads();

    int node = blockIdx.x * 256 + threadIdx.x;
    if (node >= n) return;

    int b = rowptr[node], e = rowptr[node + 1];
    float a[6] = {0.f, 0.f, 0.f, 0.f, 0.f, 0.f};
    for (int j = b; j < e; j++) {
        int s = eidx[j];
        const float2* r = (const float2*)(x + (size_t)s * 6);
        float2 r0 = r[0], r1 = r[1], r2 = r[2];
        a[0] += r0.x; a[1] += r0.y; a[2] += r1.x;
        a[3] += r1.y; a[4] += r2.x; a[5] += r2.y;
    }
    float invd = 1.0f / fmaxf((float)(e - b), 1.0f);

    const float2* xr2 = (const float2*)(x + (size_t)node * 6);
    float2 x0 = xr2[0], x1 = xr2[1], x2 = xr2[2];
    float hh[6] = {x0.x, x0.y, x1.x, x1.y, x2.x, x2.y};

    float4 acc[16];
#pragma unroll
    for (int cg = 0; cg < 16; cg++) acc[cg] = ((const float4*)bias)[cg];
#pragma unroll
    for (int k = 0; k < 6; k++) {
        float am = a[k] * invd;
        float hk = hh[k];
#pragma unroll
        for (int cg = 0; cg < 16; cg++) {
            float4 wl = sWl[k * 16 + cg];
            float4 wr = sWr[k * 16 + cg];
            acc[cg].x = fmaf(am, wl.x, fmaf(hk, wr.x, acc[cg].x));
            acc[cg].y = fmaf(am, wl.y, fmaf(hk, wr.y, acc[cg].y));
            acc[cg].z = fmaf(am, wl.z, fmaf(hk, wr.z, acc[cg].z));
            acc[cg].w = fmaf(am, wl.w, fmaf(hk, wr.w, acc[cg].w));
        }
    }
    float4* orow = (float4*)(out + (size_t)node * 64);
#pragma unroll
    for (int cg = 0; cg < 16; cg++) orow[cg] = acc[cg];
}

// ---- BN stats (separate pass — layer 1 only) ------------------------------
__global__ __launch_bounds__(256) void bn_stats(const float* __restrict__ h,
                                                float* __restrict__ stats, size_t total)
{
    __shared__ float ls[64], lss[64];
    if (threadIdx.x < 64) { ls[threadIdx.x] = 0.f; lss[threadIdx.x] = 0.f; }
    __syncthreads();
    float s = 0.f, ss = 0.f;
    size_t stride = (size_t)gridDim.x * 256;
    for (size_t i = (size_t)blockIdx.x * 256 + threadIdx.x; i < total; i += stride) {
        float v = h[i];
        s += v;
        ss = fmaf(v, v, ss);
    }
    int c = threadIdx.x & 63;
    atomicAdd(&ls[c], s);
    atomicAdd(&lss[c], ss);
    __syncthreads();
    if (threadIdx.x < 64) {
        unsafeAtomicAdd(&stats[threadIdx.x], ls[threadIdx.x]);
        unsafeAtomicAdd(&stats[64 + threadIdx.x], lss[threadIdx.x]);
    }
}

// ---- stats_reduce: fold 64 scratch slots into stats[128] ------------------
__global__ __launch_bounds__(128) void stats_reduce(const float* __restrict__ tmp,
                                                    float* __restrict__ stats)
{
    int t = threadIdx.x;       // 0..127
    float s = 0.f;
#pragma unroll 8
    for (int k = 0; k < 64; k++) s += tmp[k * 128 + t];
    stats[t] = s;
}

// ---- bn_dual: v = relu(bn(h)); h16 = fp16(v) (mm self-term), h8 = fp8(v)
//      (gather rows). 4 channels per thread.
__global__ __launch_bounds__(256) void bn_dual(const float* __restrict__ h,
                                               const float* __restrict__ stats,
                                               const float* __restrict__ g,
                                               const float* __restrict__ be,
                                               __half* __restrict__ h16,
                                               unsigned* __restrict__ h8,
                                               float invN, size_t total)
{
    size_t i4 = (size_t)blockIdx.x * 256 + threadIdx.x;
    if (i4 * 4 >= total) return;
    int c0 = (int)((i4 * 4) & 63);       // multiple of 4
    float v[4];
    float4 hv = ((const float4*)h)[i4];
    float hh[4] = {hv.x, hv.y, hv.z, hv.w};
#pragma unroll
    for (int j = 0; j < 4; j++) {
        int c = c0 + j;
        float mu  = stats[c] * invN;
        float var = stats[64 + c] * invN - mu * mu;
        float sc  = g[c] / sqrtf(var + EPS_BN);
        float sh  = fmaf(-mu, sc, be[c]);
        v[j] = fmaxf(fmaf(hh[j], sc, sh), 0.f);
    }
    float2 o16;
    ((__half2*)&o16)[0] = __floats2half2_rn(v[0], v[1]);
    ((__half2*)&o16)[1] = __floats2half2_rn(v[2], v[3]);
    ((float2*)h16)[i4] = o16;
    int p = __builtin_amdgcn_cvt_pk_fp8_f32(v[0], v[1], 0, false);
    p     = __builtin_amdgcn_cvt_pk_fp8_f32(v[2], v[3], p, true);
    h8[i4] = (unsigned)p;
}

// ---- fused aggregation + MFMA GEMM + BN stats -----------------------------
// Wave = 16-node tile. Gather phase: 4 rounds x (4 nodes x 16 lanes), R17
// structure (group-uniform eidx, fp8 rows, no shfl); mean stored fp16 into
// per-wave LDS tile (stride 72 halves -> 16B-aligned b128 fragment reads).
// GEMM phase: A(agg) fragments from LDS, A(self) from global h16; identical
// MFMA + 64-slot stats epilogue.
#define TSTRIDE 72
__global__ __launch_bounds__(256) void agg_mm_mfma(
    const int* __restrict__ rowptr, const int* __restrict__ eidx,
    const unsigned* __restrict__ h8, const __half* __restrict__ h16,
    const __half* __restrict__ wfh, const float* __restrict__ bias,
    float* __restrict__ out, float* __restrict__ statsTmp, int n)
{
    __shared__ float ls[64], lss[64];
    __shared__ _Float16 sT[4][16 * TSTRIDE];   // 4 waves x 16 nodes x 64ch
    int t = threadIdx.x;
    if (t < 64) { ls[t] = 0.f; lss[t] = 0.f; }

    int wv = t >> 6, lane = t & 63;
    int node0 = (blockIdx.x * 4 + wv) * 16;

    // ---- gather phase ----
    int grp = lane >> 4, cq = lane & 15;
#pragma unroll 1
    for (int r = 0; r < 4; r++) {
        int node = node0 + r * 4 + grp;
        int b = 0, e = 0;
        if (node < n) { b = rowptr[node]; e = rowptr[node + 1]; }

        float4 a0 = {0,0,0,0}, a1 = {0,0,0,0}, a2 = {0,0,0,0}, a3 = {0,0,0,0};
#define EDGE(S, ACC)                                                            \
        {                                                                       \
            unsigned r_ = h8[(size_t)(S) * 16 + cq];                            \
            f32x2 lo_ = __builtin_amdgcn_cvt_pk_f32_fp8(r_, false);             \
            f32x2 hi_ = __builtin_amdgcn_cvt_pk_f32_fp8(r_, true);              \
            ACC.x += lo_[0]; ACC.y += lo_[1]; ACC.z += hi_[0]; ACC.w += hi_[1]; \
        }
        int j = b;
        for (; j + 4 <= e; j += 4) {
            int s0 = eidx[j], s1 = eidx[j + 1], s2 = eidx[j + 2], s3 = eidx[j + 3];
            EDGE(s0, a0) EDGE(s1, a1) EDGE(s2, a2) EDGE(s3, a3)
        }
        for (; j < e; j++) {
            int s = eidx[j];
            EDGE(s, a0)
        }
#undef EDGE
        float ax = a0.x + a1.x + a2.x + a3.x;
        float ay = a0.y + a1.y + a2.y + a3.y;
        float az = a0.z + a1.z + a2.z + a3.z;
        float aw = a0.w + a1.w + a2.w + a3.w;
        float invd = 1.0f / fmaxf((float)(e - b), 1.0f);
        __half2 o01 = __floats2half2_rn(ax * invd, ay * invd);
        __half2 o23 = __floats2half2_rn(az * invd, aw * invd);
        float2 ov;
        ((__half2*)&ov)[0] = o01;
        ((__half2*)&ov)[1] = o23;
        *(float2*)(&sT[wv][(r * 4 + grp) * TSTRIDE + cq * 4]) = ov;
    }
    __syncthreads();    // drains LDS writes (also covers ls/lss init)

    // ---- GEMM phase ----
    int m = lane & 15, quad = lane >> 4;
    if (node0 < n) {
        const f16x8* wf = (const f16x8*)wfh;   // frag idx ((q*4+tt)*4+quad)*16+m

        int nodeA = node0 + m;
        if (nodeA >= n) nodeA = n - 1;         // tail-safe global loads

        const _Float16* hrow = (const _Float16*)(h16 + (size_t)nodeA * 64);
        f16x8 af[4];
        af[0] = *(const f16x8*)(&sT[wv][m * TSTRIDE + quad * 8]);
        af[1] = *(const f16x8*)(&sT[wv][m * TSTRIDE + 32 + quad * 8]);
        af[2] = *(const f16x8*)(hrow + quad * 8);
        af[3] = *(const f16x8*)(hrow + 32 + quad * 8);

#pragma unroll
        for (int tt = 0; tt < 4; tt++) {
            float bv = bias[tt * 16 + m];
            f32x4 c = {bv, bv, bv, bv};
#pragma unroll
            for (int q = 0; q < 4; q++)
                c = __builtin_amdgcn_mfma_f32_16x16x32_f16(
                        af[q], wf[((q * 4 + tt) * 4 + quad) * 16 + m], c, 0, 0, 0);
            float s = 0.f, ss = 0.f;
#pragma unroll
            for (int r = 0; r < 4; r++) {
                int row = node0 + quad * 4 + r;
                float v = (row < n) ? c[r] : 0.f;
                if (row < n) out[(size_t)row * 64 + tt * 16 + m] = v;
                s += v;
                ss = fmaf(v, v, ss);
            }
            s  += __shfl_xor(s, 16, 64);  s  += __shfl_xor(s, 32, 64);
            ss += __shfl_xor(ss, 16, 64); ss += __shfl_xor(ss, 32, 64);
            if (quad == 0) {
                atomicAdd(&ls[tt * 16 + m], s);
                atomicAdd(&lss[tt * 16 + m], ss);
            }
        }
    }
    __syncthreads();
    if (t < 64) {
        float* slot = statsTmp + (size_t)(blockIdx.x & 63) * 128;
        unsafeAtomicAdd(&slot[t], ls[t]);
        unsafeAtomicAdd(&slot[64 + t], lss[t]);
    }
}

// ---- fused layer-3 BN+ReLU + attention-weighted segment pooling -----------
__global__ __launch_bounds__(256) void bn_pool(
    const float* __restrict__ h, const float* __restrict__ stats,
    const float* __restrict__ g, const float* __restrict__ be,
    const float* __restrict__ x, const int* __restrict__ batch,
    float* __restrict__ rawpool, float invN, int N, int chunk)
{
    int wid  = blockIdx.x * 4 + (threadIdx.x >> 6);
    int lane = threadIdx.x & 63;
    int i0 = wid * chunk;
    if (i0 >= N) return;
    int i1 = min(i0 + chunk, N);

    float mu  = stats[lane] * invN;
    float var = stats[64 + lane] * invN - mu * mu;
    float sc  = g[lane] / sqrtf(var + EPS_BN);
    float sh  = fmaf(-mu, sc, be[lane]);

    int   cur = batch[i0];
    float acc = 0.f;
    for (int i = i0; i < i1; i++) {
        int bi = batch[i];
        if (bi != cur) {
            unsafeAtomicAdd(&rawpool[cur * 64 + lane], acc);
            acc = 0.f;
            cur = bi;
        }
        float w = expf(x[(size_t)i * 6 + 4]);
        float v = fmaxf(fmaf(h[(size_t)i * 64 + lane], sc, sh), 0.f);
        acc = fmaf(v, w, acc);
    }
    unsafeAtomicAdd(&rawpool[cur * 64 + lane], acc);
}

// ---- softmax denominator (shift-invariant: min-sub + 1e-8 drop out) -------
__global__ __launch_bounds__(256) void softmax_sum(const float* __restrict__ x,
                                                   float* __restrict__ sumexp, int n)
{
    float s = 0.f;
    int stride = gridDim.x * 256;
    for (int i = blockIdx.x * 256 + threadIdx.x; i < n; i += stride)
        s += expf(x[(size_t)i * 6 + 4]);
#pragma unroll
    for (int o = 32; o > 0; o >>= 1) s += __shfl_down(s, o, 64);
    __shared__ float wsum[4];
    if ((threadIdx.x & 63) == 0) wsum[threadIdx.x >> 6] = s;
    __syncthreads();
    if (threadIdx.x == 0)
        unsafeAtomicAdd(sumexp, wsum[0] + wsum[1] + wsum[2] + wsum[3]);
}

__global__ void seg_bounds(const int* __restrict__ batch, int* __restrict__ lb, int n)
{
    int b = threadIdx.x;
    if (b > 64) return;
    int lo = 0, hi = n;
    while (lo < hi) {
        int mid = (lo + hi) >> 1;
        if (batch[mid] < b) lo = mid + 1; else hi = mid;
    }
    lb[b] = lo;
}

// ---- heads: normalize rawpool by 1/sumexp and counts, then 2 tiny MLPs ----
__global__ __launch_bounds__(64) void heads_kernel(
    const float* __restrict__ rawpool, const float* __restrict__ sumexp,
    const int* __restrict__ lb,
    const float* __restrict__ phW1, const float* __restrict__ phb1,
    const float* __restrict__ phW2, const float* __restrict__ phb2,
    const float* __restrict__ trW1, const float* __restrict__ trb1,
    const float* __restrict__ trW2, const float* __restrict__ trb2,
    float* __restrict__ out)
{
    int b = blockIdx.x, t = threadIdx.x;
    __shared__ float p[64], h1[32], h2[16];
    float cnt = (float)(lb[b + 1] - lb[b]);
    p[t] = rawpool[b * 64 + t] / (sumexp[0] * fmaxf(cnt, 1.0f));
    __syncthreads();
    if (t < 32) {
        float s = phb1[t];
        for (int k = 0; k < 64; k++) s = fmaf(p[k], phW1[k * 32 + t], s);
        h1[t] = fmaxf(s, 0.f);
    } else if (t < 48) {
        int tt = t - 32;
        float s = trb1[tt];
        for (int k = 0; k < 64; k++) s = fmaf(p[k], trW1[k * 16 + tt], s);
        h2[tt] = fmaxf(s, 0.f);
    }
    __syncthreads();
    if (t < 3) {
        float s = phb2[t];
        for (int k = 0; k < 32; k++) s = fmaf(h1[k], phW2[k * 3 + t], s);
        out[b * 3 + t] = s;
    } else if (t == 63) {
        float s = trb2[0];
        for (int k = 0; k < 16; k++) s = fmaf(h2[k], trW2[k], s);
        out[192 + b] = 1.0f / (1.0f + expf(-s));
    }
}

extern "C" void kernel_launch(void* const* d_in, const int* in_sizes, int n_in,
                              void* d_out, int out_size, void* d_ws, size_t ws_size,
                              hipStream_t stream)
{
    const float* x     = (const float*)d_in[0];
    const int*   ei    = (const int*)d_in[1];
    const int*   batch = (const int*)d_in[2];
    const float* W1l = (const float*)d_in[3];
    const float* b1  = (const float*)d_in[4];
    const float* W1r = (const float*)d_in[5];
    const float* W2l = (const float*)d_in[6];
    const float* b2  = (const float*)d_in[7];
    const float* W2r = (const float*)d_in[8];
    const float* W3l = (const float*)d_in[9];
    const float* b3  = (const float*)d_in[10];
    const float* W3r = (const float*)d_in[11];
    const float* g1  = (const float*)d_in[12];
    const float* be1 = (const float*)d_in[13];
    const float* g2  = (const float*)d_in[14];
    const float* be2 = (const float*)d_in[15];
    const float* g3  = (const float*)d_in[16];
    const float* be3 = (const float*)d_in[17];
    const float* phW1 = (const float*)d_in[18];
    const float* phb1 = (const float*)d_in[19];
    const float* phW2 = (const float*)d_in[20];
    const float* phb2 = (const float*)d_in[21];
    const float* trW1 = (const float*)d_in[22];
    const float* trb1 = (const float*)d_in[23];
    const float* trW2 = (const float*)d_in[24];
    const float* trb2 = (const float*)d_in[25];

    const int N = in_sizes[0] / 6;
    const int E = in_sizes[1] / 2;
    const int* src = ei;
    const int* dst = ei + E;

    const int NB    = (N + 255) >> 8;          // 391 buckets
    const int nBlkA = (E + EPB - 1) / EPB;     // 196 partition blocks

    float* ws = (float*)d_ws;
    const size_t N64 = (size_t)N * 64;
    float*  hA      = ws;                          // N*64 fp32 (h1 raw, then h3 raw)
    float*  hB      = ws + N64;                    // N*64 fp32 (h2 raw)
    __half* agg16   = (__half*)(ws + 2 * N64);     // N*64 fp16 (unused in R20)
    __half* h16     = (__half*)(ws + 2 * N64 + N64 / 2);  // N*64 fp16
    int*   epck     = (int*)(ws + 3 * N64);        // E packed src|dl<<24
    int*   eidx     = epck + E;                    // E (CSR by dst)
    int*   blockBin = eidx + E;                    // nBlkA * NBIN
    // --- contiguous zero region: binTotal + stats + statsTmp + rawpool + sumexp
    int*   binTotal = blockBin + (size_t)nBlkA * NBIN;   // NBIN
    float* stats    = (float*)(binTotal + NBIN);   // 3 * 128
    float* statsTmp = stats + 384;                 // 2 * 64 * 128
    float* rawpool  = statsTmp + 16384;            // 64*64
    float* sumexp   = rawpool + 4096;              // 1 (pad 4)
    // --- end zero region ---
    int*   binBase  = (int*)(sumexp + 4);          // NBIN + 1
    int*   rowptr   = binBase + NBIN + 1;          // N + 1
    int*   lb       = rowptr + N + 1;              // 65 (pad 72)
    __half* wfrag2  = (__half*)(lb + 72);          // 8192 fp16
    __half* wfrag3  = wfrag2 + 8192;               // 8192 fp16
    unsigned* h8    = (unsigned*)(wfrag3 + 8192);  // N*16 dwords (fp8 rows)
    float* out      = (float*)d_out;
    (void)agg16;

    const int nodeBlocks = (N + 255) / 256;
    const int mfmaBlocks = (N + 63) / 64;          // 1563 (4 x 16-node tiles/block)
    const int cvt4Blocks = (int)((N64 / 4 + 255) / 256);
    const int PBLK = 1024;                         // bn_pool blocks (4 waves each)
    const int chunk = (N + PBLK * 4 - 1) / (PBLK * 4);
    const float invN = 1.0f / (float)N;

    // ---- zero accumulators; independent reductions + weight packing first
    size_t zbytes = (char*)(sumexp + 4) - (char*)binTotal;
    hipMemsetAsync(binTotal, 0, zbytes, stream);
    softmax_sum<<<256, 256, 0, stream>>>(x, sumexp, N);
    seg_bounds<<<1, 128, 0, stream>>>(batch, lb, N);
    w_prep<<<32, 256, 0, stream>>>(W2l, W2r, wfrag2);
    w_prep<<<32, 256, 0, stream>>>(W3l, W3r, wfrag3);

    // ---- CSR build via bucket partition ----
    bucket_hist<<<nBlkA, 256, 0, stream>>>(dst, blockBin, binTotal, E);
    bin_scan_totals<<<1, NBIN, 0, stream>>>(binTotal, binBase, rowptr + N);
    blockbin_offs<<<NBIN / 4, 256, 0, stream>>>(blockBin, binBase, nBlkA);
    bucket_scatter<<<nBlkA, 256, 0, stream>>>(src, dst, blockBin, epck, E);
    csr_local<<<NB, 256, 0, stream>>>(epck, binBase, rowptr, eidx, N);

    // ---- layer 1: agg6 + matmul -> hA raw; stats1; h16+h8 ----
    sage1_fused<<<nodeBlocks, 256, 0, stream>>>(rowptr, eidx, x, W1l, b1, W1r, hA, N);
    bn_stats<<<1024, 256, 0, stream>>>(hA, stats, N64);
    bn_dual<<<cvt4Blocks, 256, 0, stream>>>(hA, stats, g1, be1, h16, h8, invN, N64);

    // ---- layer 2 (fused gather+GEMM; stats2 -> 64-slot scratch) ----
    agg_mm_mfma<<<mfmaBlocks, 256, 0, stream>>>(rowptr, eidx, h8, h16, wfrag2, b2,
                                                hB, statsTmp, N);
    stats_reduce<<<1, 128, 0, stream>>>(statsTmp, stats + 128);
    bn_dual<<<cvt4Blocks, 256, 0, stream>>>(hB, stats + 128, g2, be2, h16, h8,
                                            invN, N64);

    // ---- layer 3 (fused gather+GEMM; stats3 -> 64-slot scratch) ----
    agg_mm_mfma<<<mfmaBlocks, 256, 0, stream>>>(rowptr, eidx, h8, h16, wfrag3, b3,
                                                hA, statsTmp + 8192, N);
    stats_reduce<<<1, 128, 0, stream>>>(statsTmp + 8192, stats + 256);

    // ---- fused BN3 + attention pooling + heads ----
    bn_pool<<<PBLK, 256, 0, stream>>>(hA, stats + 256, g3, be3, x, batch,
                                      rawpool, invN, N, chunk);
    heads_kernel<<<64, 64, 0, stream>>>(rawpool, sumexp, lb,
                                        phW1, phb1, phW2, phb2,
                                        trW1, trb1, trW2, trb2, out);
}

// Round 21
// 363.718 us; speedup vs baseline: 1.1537x; 1.0249x over previous
//
#include <hip/hip_runtime.h>
#include <hip/hip_fp16.h>
#include <cstdint>
#include <cstddef>

// ---------------------------------------------------------------------------
// TopoGNN: 3x SAGEConv(mean) + BN + ReLU, softmax-attention pooling, 2 heads.
// N=100000 nodes, E=1600000 edges, B=64 segments, IN_CH=6, HID=64.
// R5 (754us) bucket-CSR. R7 (644us) bn_pool. R8 (593us) split matmul+BN-fly.
// R9 (529us) fp16 rows. R12 (474us) MFMA GEMM. R15 (409us) stats 64-slot.
// R17/R19 (381us) group-per-node fp8 gather. R20 (373us): agg fused into
//     MFMA GEMM via per-wave LDS tile (agg16 round-trip gone).
// R21: dispatch-count reduction (19 -> 15): prep_kernel merges softmax_sum +
//     seg_bounds + w_prep x2 (block-range partition); blockbin_offs absorbs
//     bin_scan_totals (each block redundantly scans the 512 bin totals in
//     LDS; block 0 publishes binBase/rowptr[N]). Hot kernels byte-identical.
// ---------------------------------------------------------------------------

#define EPB 8192   // edges per partition block (256 thr x 32)
#define NBIN 512   // padded bucket count (actual NB = ceil(N/256) <= 512)
#define EPS_BN 1e-5f

typedef _Float16 f16x8 __attribute__((ext_vector_type(8)));
typedef float    f32x4 __attribute__((ext_vector_type(4)));
typedef float    f32x2 __attribute__((ext_vector_type(2)));

// ---- phase A: per-block bucket histogram ---------------------------------
__global__ __launch_bounds__(256) void bucket_hist(const int* __restrict__ dst,
                                                   int* __restrict__ blockBin,
                                                   int* __restrict__ binTotal, int E)
{
    __shared__ int hist[NBIN];
    int t = threadIdx.x;
    for (int i = t; i < NBIN; i += 256) hist[i] = 0;
    __syncthreads();
    int e0 = blockIdx.x * EPB;
#pragma unroll
    for (int k = 0; k < 32; k++) {
        int e = e0 + (k << 8) + t;
        if (e < E) atomicAdd(&hist[dst[e] >> 8], 1);
    }
    __syncthreads();
    for (int i = t; i < NBIN; i += 256) {
        int c = hist[i];
        blockBin[blockIdx.x * NBIN + i] = c;
        if (c) atomicAdd(&binTotal[i], c);
    }
}

// ---- phase B (merged): per-block redundant scan of bin totals + per-bin
//      exclusive scan over block counts. 64 blocks x 512 threads (8 waves).
//      Block 0 publishes binBase[0..NBIN] and rowptr[N]=E.
__global__ __launch_bounds__(512) void blockbin_offs(int* __restrict__ blockBin,
                                                     const int* __restrict__ binTotal,
                                                     int* __restrict__ binBase,
                                                     int* __restrict__ rowptrN,
                                                     int nBlk)
{
    __shared__ int s[NBIN];
    int t = threadIdx.x;
    int tot = binTotal[t];
    s[t] = tot;
    __syncthreads();
    for (int off = 1; off < NBIN; off <<= 1) {
        int v = (t >= off) ? s[t - off] : 0;
        __syncthreads();
        s[t] += v;
        __syncthreads();
    }
    int excl = s[t] - tot;
    if (blockIdx.x == 0) {
        binBase[t] = excl;
        if (t == NBIN - 1) { binBase[NBIN] = s[t]; *rowptrN = s[t]; }
    }
    __syncthreads();

    int wv   = t >> 6;              // 0..7
    int lane = t & 63;
    int bin  = blockIdx.x * 8 + wv;
    int carry = s[bin] - binTotal[bin];   // exclusive base for this bin
    for (int c0 = 0; c0 < nBlk; c0 += 64) {
        int blk = c0 + lane;
        int cnt = (blk < nBlk) ? blockBin[blk * NBIN + bin] : 0;
        int v = cnt;
#pragma unroll
        for (int d = 1; d < 64; d <<= 1) {
            int u = __shfl_up(v, d, 64);
            if (lane >= d) v += u;
        }
        if (blk < nBlk) blockBin[blk * NBIN + bin] = carry + v - cnt;
        carry += __shfl(v, 63, 64);
    }
}

// ---- phase C: place packed (src | local_dst<<24); per-block LDS cursors ---
__global__ __launch_bounds__(256) void bucket_scatter(const int* __restrict__ src,
                                                      const int* __restrict__ dst,
                                                      const int* __restrict__ blockBin,
                                                      int* __restrict__ epck, int E)
{
    __shared__ int cur[NBIN];
    int t = threadIdx.x;
    for (int i = t; i < NBIN; i += 256) cur[i] = blockBin[blockIdx.x * NBIN + i];
    __syncthreads();
    int e0 = blockIdx.x * EPB;
#pragma unroll
    for (int k = 0; k < 32; k++) {
        int e = e0 + (k << 8) + t;
        if (e < E) {
            int d = dst[e];
            int pos = atomicAdd(&cur[d >> 8], 1);
            epck[pos] = src[e] | ((d & 255) << 24);   // src < 2^24
        }
    }
}

// ---- phase D: per-bucket local CSR --------------------------------------
__global__ __launch_bounds__(256) void csr_local(const int* __restrict__ epck,
                                                 const int* __restrict__ binBase,
                                                 int* __restrict__ rowptr,
                                                 int* __restrict__ eidx, int N)
{
    __shared__ int cnt[256], s[256], cur[256];
    int t = threadIdx.x, bkt = blockIdx.x;
    int base = binBase[bkt], nE = binBase[bkt + 1] - base;
    cnt[t] = 0;
    __syncthreads();
    for (int j = t; j < nE; j += 256)
        atomicAdd(&cnt[(unsigned)epck[base + j] >> 24], 1);
    __syncthreads();
    s[t] = cnt[t];
    __syncthreads();
    for (int off = 1; off < 256; off <<= 1) {
        int v = (t >= off) ? s[t - off] : 0;
        __syncthreads();
        s[t] += v;
        __syncthreads();
    }
    int excl = s[t] - cnt[t];
    cur[t] = excl;
    int node = (bkt << 8) + t;
    if (node < N) rowptr[node] = base + excl;
    __syncthreads();
    for (int j = t; j < nE; j += 256) {
        int v = epck[base + j];
        int pos = atomicAdd(&cur[(unsigned)v >> 24], 1);
        eidx[base + pos] = v & 0xFFFFFF;     // contiguous 16KB span: stays in L2
    }
}

// ---- prep: softmax denominator (blocks 0-255), seg_bounds (block 256),
//      w_prep for wfrag2 (257-288) and wfrag3 (289-320). ------------------
__global__ __launch_bounds__(256) void prep_kernel(
    const float* __restrict__ x, float* __restrict__ sumexp, int n,
    const int* __restrict__ batch, int* __restrict__ lb,
    const float* __restrict__ W2l, const float* __restrict__ W2r,
    const float* __restrict__ W3l, const float* __restrict__ W3r,
    __half* __restrict__ wfrag2, __half* __restrict__ wfrag3)
{
    int bid = blockIdx.x, t = threadIdx.x;
    if (bid < 256) {
        float s = 0.f;
        int stride = 256 * 256;
        for (int i = bid * 256 + t; i < n; i += stride)
            s += expf(x[(size_t)i * 6 + 4]);
#pragma unroll
        for (int o = 32; o > 0; o >>= 1) s += __shfl_down(s, o, 64);
        __shared__ float wsum[4];
        if ((t & 63) == 0) wsum[t >> 6] = s;
        __syncthreads();
        if (t == 0)
            unsafeAtomicAdd(sumexp, wsum[0] + wsum[1] + wsum[2] + wsum[3]);
    } else if (bid == 256) {
        int b = t;
        if (b > 64) return;
        int lo = 0, hi = n;
        while (lo < hi) {
            int mid = (lo + hi) >> 1;
            if (batch[mid] < b) lo = mid + 1; else hi = mid;
        }
        lb[b] = lo;
    } else {
        bool second = (bid >= 289);
        int i = (bid - (second ? 289 : 257)) * 256 + t;
        if (i >= 8192) return;
        int j    = i & 7;
        int m    = (i >> 3) & 15;
        int quad = (i >> 7) & 3;
        int tt   = (i >> 9) & 3;
        int q    = i >> 11;
        int k    = (q & 1) * 32 + quad * 8 + j;
        int col  = tt * 16 + m;
        const float* W = second ? ((q < 2) ? W3l : W3r)
                                : ((q < 2) ? W2l : W2r);
        (second ? wfrag3 : wfrag2)[i] = __float2half_rn(W[k * 64 + col]);
    }
}

// ---- layer 1: fused pull-aggregation (6 ch) + matmul (thread-per-node) ----
__global__ __launch_bounds__(256) void sage1_fused(
    const int* __restrict__ rowptr, const int* __restrict__ eidx,
    const float* __restrict__ x,
    const float* __restrict__ Wl, const float* __restrict__ bias,
    const float* __restrict__ Wr, float* __restrict__ out, int n)
{
    __shared__ float4 sWl[6 * 16];
    __shared__ float4 sWr[6 * 16];
    for (int i = threadIdx.x; i < 6 * 16; i += 256) {
        sWl[i] = ((const float4*)Wl)[i];
        sWr[i] = ((const float4*)Wr)[i];
    }
    __syncthreads();

    int node = blockIdx.x * 256 + threadIdx.x;
    if (node >= n) return;

    int b = rowptr[node], e = rowptr[node + 1];
    float a[6] = {0.f, 0.f, 0.f, 0.f, 0.f, 0.f};
    for (int j = b; j < e; j++) {
        int s = eidx[j];
        const float2* r = (const float2*)(x + (size_t)s * 6);
        float2 r0 = r[0], r1 = r[1], r2 = r[2];
        a[0] += r0.x; a[1] += r0.y; a[2] += r1.x;
        a[3] += r1.y; a[4] += r2.x; a[5] += r2.y;
    }
    float invd = 1.0f / fmaxf((float)(e - b), 1.0f);

    const float2* xr2 = (const float2*)(x + (size_t)node * 6);
    float2 x0 = xr2[0], x1 = xr2[1], x2 = xr2[2];
    float hh[6] = {x0.x, x0.y, x1.x, x1.y, x2.x, x2.y};

    float4 acc[16];
#pragma unroll
    for (int cg = 0; cg < 16; cg++) acc[cg] = ((const float4*)bias)[cg];
#pragma unroll
    for (int k = 0; k < 6; k++) {
        float am = a[k] * invd;
        float hk = hh[k];
#pragma unroll
        for (int cg = 0; cg < 16; cg++) {
            float4 wl = sWl[k * 16 + cg];
            float4 wr = sWr[k * 16 + cg];
            acc[cg].x = fmaf(am, wl.x, fmaf(hk, wr.x, acc[cg].x));
            acc[cg].y = fmaf(am, wl.y, fmaf(hk, wr.y, acc[cg].y));
            acc[cg].z = fmaf(am, wl.z, fmaf(hk, wr.z, acc[cg].z));
            acc[cg].w = fmaf(am, wl.w, fmaf(hk, wr.w, acc[cg].w));
        }
    }
    float4* orow = (float4*)(out + (size_t)node * 64);
#pragma unroll
    for (int cg = 0; cg < 16; cg++) orow[cg] = acc[cg];
}

// ---- BN stats (separate pass — layer 1 only) ------------------------------
__global__ __launch_bounds__(256) void bn_stats(const float* __restrict__ h,
                                                float* __restrict__ stats, size_t total)
{
    __shared__ float ls[64], lss[64];
    if (threadIdx.x < 64) { ls[threadIdx.x] = 0.f; lss[threadIdx.x] = 0.f; }
    __syncthreads();
    float s = 0.f, ss = 0.f;
    size_t stride = (size_t)gridDim.x * 256;
    for (size_t i = (size_t)blockIdx.x * 256 + threadIdx.x; i < total; i += stride) {
        float v = h[i];
        s += v;
        ss = fmaf(v, v, ss);
    }
    int c = threadIdx.x & 63;
    atomicAdd(&ls[c], s);
    atomicAdd(&lss[c], ss);
    __syncthreads();
    if (threadIdx.x < 64) {
        unsafeAtomicAdd(&stats[threadIdx.x], ls[threadIdx.x]);
        unsafeAtomicAdd(&stats[64 + threadIdx.x], lss[threadIdx.x]);
    }
}

// ---- stats_reduce: fold 64 scratch slots into stats[128] ------------------
__global__ __launch_bounds__(128) void stats_reduce(const float* __restrict__ tmp,
                                                    float* __restrict__ stats)
{
    int t = threadIdx.x;       // 0..127
    float s = 0.f;
#pragma unroll 8
    for (int k = 0; k < 64; k++) s += tmp[k * 128 + t];
    stats[t] = s;
}

// ---- bn_dual: v = relu(bn(h)); h16 = fp16(v) (mm self-term), h8 = fp8(v)
//      (gather rows). 4 channels per thread.
__global__ __launch_bounds__(256) void bn_dual(const float* __restrict__ h,
                                               const float* __restrict__ stats,
                                               const float* __restrict__ g,
                                               const float* __restrict__ be,
                                               __half* __restrict__ h16,
                                               unsigned* __restrict__ h8,
                                               float invN, size_t total)
{
    size_t i4 = (size_t)blockIdx.x * 256 + threadIdx.x;
    if (i4 * 4 >= total) return;
    int c0 = (int)((i4 * 4) & 63);       // multiple of 4
    float v[4];
    float4 hv = ((const float4*)h)[i4];
    float hh[4] = {hv.x, hv.y, hv.z, hv.w};
#pragma unroll
    for (int j = 0; j < 4; j++) {
        int c = c0 + j;
        float mu  = stats[c] * invN;
        float var = stats[64 + c] * invN - mu * mu;
        float sc  = g[c] / sqrtf(var + EPS_BN);
        float sh  = fmaf(-mu, sc, be[c]);
        v[j] = fmaxf(fmaf(hh[j], sc, sh), 0.f);
    }
    float2 o16;
    ((__half2*)&o16)[0] = __floats2half2_rn(v[0], v[1]);
    ((__half2*)&o16)[1] = __floats2half2_rn(v[2], v[3]);
    ((float2*)h16)[i4] = o16;
    int p = __builtin_amdgcn_cvt_pk_fp8_f32(v[0], v[1], 0, false);
    p     = __builtin_amdgcn_cvt_pk_fp8_f32(v[2], v[3], p, true);
    h8[i4] = (unsigned)p;
}

// ---- fused aggregation + MFMA GEMM + BN stats (R20 verbatim) --------------
#define TSTRIDE 72
__global__ __launch_bounds__(256) void agg_mm_mfma(
    const int* __restrict__ rowptr, const int* __restrict__ eidx,
    const unsigned* __restrict__ h8, const __half* __restrict__ h16,
    const __half* __restrict__ wfh, const float* __restrict__ bias,
    float* __restrict__ out, float* __restrict__ statsTmp, int n)
{
    __shared__ float ls[64], lss[64];
    __shared__ _Float16 sT[4][16 * TSTRIDE];   // 4 waves x 16 nodes x 64ch
    int t = threadIdx.x;
    if (t < 64) { ls[t] = 0.f; lss[t] = 0.f; }

    int wv = t >> 6, lane = t & 63;
    int node0 = (blockIdx.x * 4 + wv) * 16;

    // ---- gather phase ----
    int grp = lane >> 4, cq = lane & 15;
#pragma unroll 1
    for (int r = 0; r < 4; r++) {
        int node = node0 + r * 4 + grp;
        int b = 0, e = 0;
        if (node < n) { b = rowptr[node]; e = rowptr[node + 1]; }

        float4 a0 = {0,0,0,0}, a1 = {0,0,0,0}, a2 = {0,0,0,0}, a3 = {0,0,0,0};
#define EDGE(S, ACC)                                                            \
        {                                                                       \
            unsigned r_ = h8[(size_t)(S) * 16 + cq];                            \
            f32x2 lo_ = __builtin_amdgcn_cvt_pk_f32_fp8(r_, false);             \
            f32x2 hi_ = __builtin_amdgcn_cvt_pk_f32_fp8(r_, true);              \
            ACC.x += lo_[0]; ACC.y += lo_[1]; ACC.z += hi_[0]; ACC.w += hi_[1]; \
        }
        int j = b;
        for (; j + 4 <= e; j += 4) {
            int s0 = eidx[j], s1 = eidx[j + 1], s2 = eidx[j + 2], s3 = eidx[j + 3];
            EDGE(s0, a0) EDGE(s1, a1) EDGE(s2, a2) EDGE(s3, a3)
        }
        for (; j < e; j++) {
            int s = eidx[j];
            EDGE(s, a0)
        }
#undef EDGE
        float ax = a0.x + a1.x + a2.x + a3.x;
        float ay = a0.y + a1.y + a2.y + a3.y;
        float az = a0.z + a1.z + a2.z + a3.z;
        float aw = a0.w + a1.w + a2.w + a3.w;
        float invd = 1.0f / fmaxf((float)(e - b), 1.0f);
        __half2 o01 = __floats2half2_rn(ax * invd, ay * invd);
        __half2 o23 = __floats2half2_rn(az * invd, aw * invd);
        float2 ov;
        ((__half2*)&ov)[0] = o01;
        ((__half2*)&ov)[1] = o23;
        *(float2*)(&sT[wv][(r * 4 + grp) * TSTRIDE + cq * 4]) = ov;
    }
    __syncthreads();    // drains LDS writes (also covers ls/lss init)

    // ---- GEMM phase ----
    int m = lane & 15, quad = lane >> 4;
    if (node0 < n) {
        const f16x8* wf = (const f16x8*)wfh;   // frag idx ((q*4+tt)*4+quad)*16+m

        int nodeA = node0 + m;
        if (nodeA >= n) nodeA = n - 1;         // tail-safe global loads

        const _Float16* hrow = (const _Float16*)(h16 + (size_t)nodeA * 64);
        f16x8 af[4];
        af[0] = *(const f16x8*)(&sT[wv][m * TSTRIDE + quad * 8]);
        af[1] = *(const f16x8*)(&sT[wv][m * TSTRIDE + 32 + quad * 8]);
        af[2] = *(const f16x8*)(hrow + quad * 8);
        af[3] = *(const f16x8*)(hrow + 32 + quad * 8);

#pragma unroll
        for (int tt = 0; tt < 4; tt++) {
            float bv = bias[tt * 16 + m];
            f32x4 c = {bv, bv, bv, bv};
#pragma unroll
            for (int q = 0; q < 4; q++)
                c = __builtin_amdgcn_mfma_f32_16x16x32_f16(
                        af[q], wf[((q * 4 + tt) * 4 + quad) * 16 + m], c, 0, 0, 0);
            float s = 0.f, ss = 0.f;
#pragma unroll
            for (int r = 0; r < 4; r++) {
                int row = node0 + quad * 4 + r;
                float v = (row < n) ? c[r] : 0.f;
                if (row < n) out[(size_t)row * 64 + tt * 16 + m] = v;
                s += v;
                ss = fmaf(v, v, ss);
            }
            s  += __shfl_xor(s, 16, 64);  s  += __shfl_xor(s, 32, 64);
            ss += __shfl_xor(ss, 16, 64); ss += __shfl_xor(ss, 32, 64);
            if (quad == 0) {
                atomicAdd(&ls[tt * 16 + m], s);
                atomicAdd(&lss[tt * 16 + m], ss);
            }
        }
    }
    __syncthreads();
    if (t < 64) {
        float* slot = statsTmp + (size_t)(blockIdx.x & 63) * 128;
        unsafeAtomicAdd(&slot[t], ls[t]);
        unsafeAtomicAdd(&slot[64 + t], lss[t]);
    }
}

// ---- fused layer-3 BN+ReLU + attention-weighted segment pooling -----------
__global__ __launch_bounds__(256) void bn_pool(
    const float* __restrict__ h, const float* __restrict__ stats,
    const float* __restrict__ g, const float* __restrict__ be,
    const float* __restrict__ x, const int* __restrict__ batch,
    float* __restrict__ rawpool, float invN, int N, int chunk)
{
    int wid  = blockIdx.x * 4 + (threadIdx.x >> 6);
    int lane = threadIdx.x & 63;
    int i0 = wid * chunk;
    if (i0 >= N) return;
    int i1 = min(i0 + chunk, N);

    float mu  = stats[lane] * invN;
    float var = stats[64 + lane] * invN - mu * mu;
    float sc  = g[lane] / sqrtf(var + EPS_BN);
    float sh  = fmaf(-mu, sc, be[lane]);

    int   cur = batch[i0];
    float acc = 0.f;
    for (int i = i0; i < i1; i++) {
        int bi = batch[i];
        if (bi != cur) {
            unsafeAtomicAdd(&rawpool[cur * 64 + lane], acc);
            acc = 0.f;
            cur = bi;
        }
        float w = expf(x[(size_t)i * 6 + 4]);
        float v = fmaxf(fmaf(h[(size_t)i * 64 + lane], sc, sh), 0.f);
        acc = fmaf(v, w, acc);
    }
    unsafeAtomicAdd(&rawpool[cur * 64 + lane], acc);
}

// ---- heads: normalize rawpool by 1/sumexp and counts, then 2 tiny MLPs ----
__global__ __launch_bounds__(64) void heads_kernel(
    const float* __restrict__ rawpool, const float* __restrict__ sumexp,
    const int* __restrict__ lb,
    const float* __restrict__ phW1, const float* __restrict__ phb1,
    const float* __restrict__ phW2, const float* __restrict__ phb2,
    const float* __restrict__ trW1, const float* __restrict__ trb1,
    const float* __restrict__ trW2, const float* __restrict__ trb2,
    float* __restrict__ out)
{
    int b = blockIdx.x, t = threadIdx.x;
    __shared__ float p[64], h1[32], h2[16];
    float cnt = (float)(lb[b + 1] - lb[b]);
    p[t] = rawpool[b * 64 + t] / (sumexp[0] * fmaxf(cnt, 1.0f));
    __syncthreads();
    if (t < 32) {
        float s = phb1[t];
        for (int k = 0; k < 64; k++) s = fmaf(p[k], phW1[k * 32 + t], s);
        h1[t] = fmaxf(s, 0.f);
    } else if (t < 48) {
        int tt = t - 32;
        float s = trb1[tt];
        for (int k = 0; k < 64; k++) s = fmaf(p[k], trW1[k * 16 + tt], s);
        h2[tt] = fmaxf(s, 0.f);
    }
    __syncthreads();
    if (t < 3) {
        float s = phb2[t];
        for (int k = 0; k < 32; k++) s = fmaf(h1[k], phW2[k * 3 + t], s);
        out[b * 3 + t] = s;
    } else if (t == 63) {
        float s = trb2[0];
        for (int k = 0; k < 16; k++) s = fmaf(h2[k], trW2[k], s);
        out[192 + b] = 1.0f / (1.0f + expf(-s));
    }
}

extern "C" void kernel_launch(void* const* d_in, const int* in_sizes, int n_in,
                              void* d_out, int out_size, void* d_ws, size_t ws_size,
                              hipStream_t stream)
{
    const float* x     = (const float*)d_in[0];
    const int*   ei    = (const int*)d_in[1];
    const int*   batch = (const int*)d_in[2];
    const float* W1l = (const float*)d_in[3];
    const float* b1  = (const float*)d_in[4];
    const float* W1r = (const float*)d_in[5];
    const float* W2l = (const float*)d_in[6];
    const float* b2  = (const float*)d_in[7];
    const float* W2r = (const float*)d_in[8];
    const float* W3l = (const float*)d_in[9];
    const float* b3  = (const float*)d_in[10];
    const float* W3r = (const float*)d_in[11];
    const float* g1  = (const float*)d_in[12];
    const float* be1 = (const float*)d_in[13];
    const float* g2  = (const float*)d_in[14];
    const float* be2 = (const float*)d_in[15];
    const float* g3  = (const float*)d_in[16];
    const float* be3 = (const float*)d_in[17];
    const float* phW1 = (const float*)d_in[18];
    const float* phb1 = (const float*)d_in[19];
    const float* phW2 = (const float*)d_in[20];
    const float* phb2 = (const float*)d_in[21];
    const float* trW1 = (const float*)d_in[22];
    const float* trb1 = (const float*)d_in[23];
    const float* trW2 = (const float*)d_in[24];
    const float* trb2 = (const float*)d_in[25];

    const int N = in_sizes[0] / 6;
    const int E = in_sizes[1] / 2;
    const int* src = ei;
    const int* dst = ei + E;

    const int NB    = (N + 255) >> 8;          // 391 buckets
    const int nBlkA = (E + EPB - 1) / EPB;     // 196 partition blocks

    float* ws = (float*)d_ws;
    const size_t N64 = (size_t)N * 64;
    float*  hA      = ws;                          // N*64 fp32 (h1 raw, then h3 raw)
    float*  hB      = ws + N64;                    // N*64 fp32 (h2 raw)
    __half* h16     = (__half*)(ws + 2 * N64 + N64 / 2);  // N*64 fp16
    int*   epck     = (int*)(ws + 3 * N64);        // E packed src|dl<<24
    int*   eidx     = epck + E;                    // E (CSR by dst)
    int*   blockBin = eidx + E;                    // nBlkA * NBIN
    // --- contiguous zero region: binTotal + stats + statsTmp + rawpool + sumexp
    int*   binTotal = blockBin + (size_t)nBlkA * NBIN;   // NBIN
    float* stats    = (float*)(binTotal + NBIN);   // 3 * 128
    float* statsTmp = stats + 384;                 // 2 * 64 * 128
    float* rawpool  = statsTmp + 16384;            // 64*64
    float* sumexp   = rawpool + 4096;              // 1 (pad 4)
    // --- end zero region ---
    int*   binBase  = (int*)(sumexp + 4);          // NBIN + 1
    int*   rowptr   = binBase + NBIN + 1;          // N + 1
    int*   lb       = rowptr + N + 1;              // 65 (pad 72)
    __half* wfrag2  = (__half*)(lb + 72);          // 8192 fp16
    __half* wfrag3  = wfrag2 + 8192;               // 8192 fp16
    unsigned* h8    = (unsigned*)(wfrag3 + 8192);  // N*16 dwords (fp8 rows)
    float* out      = (float*)d_out;

    const int nodeBlocks = (N + 255) / 256;
    const int mfmaBlocks = (N + 63) / 64;          // 1563 (4 x 16-node tiles/block)
    const int cvt4Blocks = (int)((N64 / 4 + 255) / 256);
    const int PBLK = 1024;                         // bn_pool blocks (4 waves each)
    const int chunk = (N + PBLK * 4 - 1) / (PBLK * 4);
    const float invN = 1.0f / (float)N;

    // ---- zero accumulators; merged prep (softmax + seg_bounds + w_prep x2)
    size_t zbytes = (char*)(sumexp + 4) - (char*)binTotal;
    hipMemsetAsync(binTotal, 0, zbytes, stream);
    prep_kernel<<<321, 256, 0, stream>>>(x, sumexp, N, batch, lb,
                                         W2l, W2r, W3l, W3r, wfrag2, wfrag3);

    // ---- CSR build via bucket partition (scan merged into blockbin_offs) --
    bucket_hist<<<nBlkA, 256, 0, stream>>>(dst, blockBin, binTotal, E);
    blockbin_offs<<<NBIN / 8, 512, 0, stream>>>(blockBin, binTotal, binBase,
                                                rowptr + N, nBlkA);
    bucket_scatter<<<nBlkA, 256, 0, stream>>>(src, dst, blockBin, epck, E);
    csr_local<<<NB, 256, 0, stream>>>(epck, binBase, rowptr, eidx, N);

    // ---- layer 1: agg6 + matmul -> hA raw; stats1; h16+h8 ----
    sage1_fused<<<nodeBlocks, 256, 0, stream>>>(rowptr, eidx, x, W1l, b1, W1r, hA, N);
    bn_stats<<<1024, 256, 0, stream>>>(hA, stats, N64);
    bn_dual<<<cvt4Blocks, 256, 0, stream>>>(hA, stats, g1, be1, h16, h8, invN, N64);

    // ---- layer 2 (fused gather+GEMM; stats2 -> 64-slot scratch) ----
    agg_mm_mfma<<<mfmaBlocks, 256, 0, stream>>>(rowptr, eidx, h8, h16, wfrag2, b2,
                                                hB, statsTmp, N);
    stats_reduce<<<1, 128, 0, stream>>>(statsTmp, stats + 128);
    bn_dual<<<cvt4Blocks, 256, 0, stream>>>(hB, stats + 128, g2, be2, h16, h8,
                                            invN, N64);

    // ---- layer 3 (fused gather+GEMM; stats3 -> 64-slot scratch) ----
    agg_mm_mfma<<<mfmaBlocks, 256, 0, stream>>>(rowptr, eidx, h8, h16, wfrag3, b3,
                                                hA, statsTmp + 8192, N);
    stats_reduce<<<1, 128, 0, stream>>>(statsTmp + 8192, stats + 256);

    // ---- fused BN3 + attention pooling + heads ----
    bn_pool<<<PBLK, 256, 0, stream>>>(hA, stats + 256, g3, be3, x, batch,
                                      rawpool, invN, N, chunk);
    heads_kernel<<<64, 64, 0, stream>>>(rawpool, sumexp, lb,
                                        phW1, phb1, phW2, phb2,
                                        trW1, trb1, trW2, trb2, out);
}